// Round 9
// baseline (672.318 us; speedup 1.0000x reference)
//
#include <hip/hip_runtime.h>
#include <hip/hip_bf16.h>
#include <math.h>

#define BB   4
#define TT   1024
#define DD   1024
#define HH   16
#define DII  2048
#define DSS  16
#define DCC  4
#define KK   204
#define HDD  64
#define DTRR 64
#define NCH  32
#define LCH  32    // TT / NCH
#define KSPL 8
#define XPN  96

typedef short bf16x8 __attribute__((ext_vector_type(8)));
typedef float f32x4 __attribute__((ext_vector_type(4)));

#define GLDS16(g, l) __builtin_amdgcn_global_load_lds(                        \
    (const __attribute__((address_space(1))) void*)(g),                       \
    (__attribute__((address_space(3))) void*)(l), 16, 0, 0)

__device__ __forceinline__ ushort f2bu(float v) {
  __hip_bfloat16 h = __float2bfloat16(v);
  return __builtin_bit_cast(ushort, h);
}

// ---------------- reduction helpers ----------------
__device__ __forceinline__ float wave_sum(float v) {
#pragma unroll
  for (int o = 32; o > 0; o >>= 1) v += __shfl_xor(v, o, 64);
  return v;
}
__device__ __forceinline__ float block_sum256(float v, volatile float* sh) {
  v = wave_sum(v);
  if ((threadIdx.x & 63) == 0) sh[threadIdx.x >> 6] = v;
  __syncthreads();
  float r = sh[0] + sh[1] + sh[2] + sh[3];
  __syncthreads();
  return r;
}

// ---------------- layernorm (writes fp32 + bf16) ----------------
__global__ __launch_bounds__(256) void layernorm_kernel(
    const float* __restrict__ x, const float* __restrict__ g,
    const float* __restrict__ be, float* __restrict__ xn,
    __hip_bfloat16* __restrict__ xnb) {
  __shared__ float sh[4];
  int row = blockIdx.x;
  const float* xr = x + (size_t)row * DD;
  float v[4];
  float s = 0.f;
#pragma unroll
  for (int i = 0; i < 4; i++) { v[i] = xr[threadIdx.x + 256 * i]; s += v[i]; }
  float mean = block_sum256(s, sh) * (1.f / DD);
  float q = 0.f;
#pragma unroll
  for (int i = 0; i < 4; i++) { float d = v[i] - mean; q += d * d; }
  float var = block_sum256(q, sh) * (1.f / DD);
  float rstd = rsqrtf(var + 1e-5f);
#pragma unroll
  for (int i = 0; i < 4; i++) {
    int c = threadIdx.x + 256 * i;
    float o = (v[i] - mean) * rstd * g[c] + be[c];
    xn[(size_t)row * DD + c] = o;
    xnb[(size_t)row * DD + c] = __float2bfloat16(o);
  }
}

// ---------------- transpose + convert: W[rows,cols] f32 -> WT[cols,rows] bf16 ----
__global__ __launch_bounds__(256) void transpose_bf16(
    const float* __restrict__ W, int rows, int cols,
    __hip_bfloat16* __restrict__ WT) {
  __shared__ float tile[32][33];
  int c0 = blockIdx.x * 32, r0 = blockIdx.y * 32;
  int tx = threadIdx.x & 31, ty = threadIdx.x >> 5;
#pragma unroll
  for (int i = 0; i < 32; i += 8)
    tile[ty + i][tx] = W[(size_t)(r0 + ty + i) * cols + c0 + tx];
  __syncthreads();
#pragma unroll
  for (int i = 0; i < 32; i += 8)
    WT[(size_t)(c0 + ty + i) * rows + r0 + tx] = __float2bfloat16(tile[tx][ty + i]);
}

// ---------------- 256x256 2-phase bf16 MFMA GEMM (M,N %256, K %64) ----------
// C[M,N] fp32 = A@BT^T (+bias, +addmat). 512 thr, 8 waves (2Mx4N),
// wave tile 128x64, BK=64, linear LDS + global_load_lds, XCD swizzle.
__global__ __launch_bounds__(512) void gemm_bf16_256(
    const ushort* __restrict__ A, int lda,
    const ushort* __restrict__ BT, int ldbt,
    float* __restrict__ C, int ldc, int K,
    const float* __restrict__ bias, const float* __restrict__ addmat) {
  __shared__ ushort Alds[256 * 64];   // 32 KB
  __shared__ ushort Blds[256 * 64];   // 32 KB
  int t = threadIdx.x;
  int wv = t >> 6, lane = t & 63;
  int wvm = wv >> 2, wvn = wv & 3;
  int nwg = gridDim.x * gridDim.y;
  int lin = blockIdx.y * gridDim.x + blockIdx.x;
  int swz = (lin & 7) * (nwg >> 3) + (lin >> 3);
  int bx = swz % gridDim.x, by = swz / gridDim.x;
  int row0 = by * 256, col0 = bx * 256;
  f32x4 acc[8][4] = {};

  const ushort* Ap[4];
  const ushort* Bp[4];
  ushort* Alb[4];
  ushort* Blb[4];
#pragma unroll
  for (int j = 0; j < 4; j++) {
    int c = j * 512 + t;
    int r = c >> 3, kc = (c & 7) * 8;
    Ap[j] = A + (size_t)(row0 + r) * lda + kc;
    Bp[j] = BT + (size_t)(col0 + r) * ldbt + kc;
    int cst = j * 512 + wv * 64;          // wave-uniform chunk base
    Alb[j] = Alds + (size_t)cst * 8;
    Blb[j] = Blds + (size_t)cst * 8;
  }
  int frow = lane & 15, fk = (lane >> 4) * 8;

  for (int k0 = 0; k0 < K; k0 += 64) {
#pragma unroll
    for (int j = 0; j < 4; j++) {
      GLDS16(Ap[j] + k0, Alb[j]);
      GLDS16(Bp[j] + k0, Blb[j]);
    }
    __syncthreads();
#pragma unroll
    for (int ks = 0; ks < 2; ks++) {
      bf16x8 af[8], bfv[4];
#pragma unroll
      for (int m = 0; m < 8; m++)
        af[m] = *(const bf16x8*)&Alds[(wvm * 128 + m * 16 + frow) * 64 +
                                      ks * 32 + fk];
#pragma unroll
      for (int n = 0; n < 4; n++)
        bfv[n] = *(const bf16x8*)&Blds[(wvn * 64 + n * 16 + frow) * 64 +
                                       ks * 32 + fk];
#pragma unroll
      for (int m = 0; m < 8; m++)
#pragma unroll
        for (int n = 0; n < 4; n++)
          acc[m][n] = __builtin_amdgcn_mfma_f32_16x16x32_bf16(af[m], bfv[n],
                                                              acc[m][n], 0, 0, 0);
    }
    __syncthreads();
  }
  int rbase = row0 + wvm * 128 + (lane >> 4) * 4;
  int cbase = col0 + wvn * 64 + (lane & 15);
#pragma unroll
  for (int n = 0; n < 4; n++) {
    int cc = cbase + n * 16;
    float bi = bias ? bias[cc] : 0.f;
#pragma unroll
    for (int m = 0; m < 8; m++) {
#pragma unroll
      for (int i = 0; i < 4; i++) {
        size_t r = rbase + m * 16 + i;
        float v = acc[m][n][i] + bi;
        if (addmat) v += addmat[r * ldc + cc];
        C[r * ldc + cc] = v;
      }
    }
  }
}

// ---------------- 128x128 bf16 MFMA GEMM (fp32 C) ----------------
// C[M,N] = A[M,K] @ BT[N,K]^T + bias (+addmat). rowmap: out row r ->
// (r/KK)*TT + rowmap[r] (fused top-K scatter). XCD swizzle (nwg %8==0).
__global__ __launch_bounds__(256) void gemm_bf16_mfma(
    const ushort* __restrict__ A, int lda,
    const ushort* __restrict__ BT, int ldbt,
    float* __restrict__ C, int ldc,
    int M, int N, int K, const float* __restrict__ bias,
    const float* __restrict__ addmat, const int* __restrict__ rowmap) {
  __shared__ ushort Alds[128 * 32];
  __shared__ ushort Blds[128 * 32];
  int t = threadIdx.x;
  int wv = t >> 6;
  int lane = t & 63;
  int nwg = gridDim.x * gridDim.y;
  int lin = blockIdx.y * gridDim.x + blockIdx.x;
  int swz = (lin & 7) * (nwg >> 3) + (lin >> 3);
  int bx = swz % gridDim.x, by = swz / gridDim.x;
  int row0 = by * 128, col0 = bx * 128;
  int wr = (wv >> 1) * 64, wc = (wv & 1) * 64;
  f32x4 acc[4][4] = {};

  int srow = t >> 2;
  int sk = (t & 3) * 8;
  int ar0 = row0 + srow;       if (ar0 >= M) ar0 = M - 1;
  int ar1 = row0 + 64 + srow;  if (ar1 >= M) ar1 = M - 1;
  int br0 = col0 + srow;       if (br0 >= N) br0 = N - 1;
  int br1 = col0 + 64 + srow;  if (br1 >= N) br1 = N - 1;
  const ushort* Ag0 = A + (size_t)ar0 * lda + sk;
  const ushort* Ag1 = A + (size_t)ar1 * lda + sk;
  const ushort* Bg0 = BT + (size_t)br0 * ldbt + sk;
  const ushort* Bg1 = BT + (size_t)br1 * ldbt + sk;
  ushort* Al = Alds + wv * 512;
  ushort* Bl = Blds + wv * 512;

  int frow = lane & 15;
  int fk = (lane >> 4) * 8;

  for (int k0 = 0; k0 < K; k0 += 32) {
    GLDS16(Ag0 + k0, Al);
    GLDS16(Ag1 + k0, Al + 2048);
    GLDS16(Bg0 + k0, Bl);
    GLDS16(Bg1 + k0, Bl + 2048);
    __syncthreads();
    bf16x8 af[4], bfv[4];
#pragma unroll
    for (int m = 0; m < 4; m++)
      af[m] = *(const bf16x8*)&Alds[(wr + m * 16 + frow) * 32 + fk];
#pragma unroll
    for (int n = 0; n < 4; n++)
      bfv[n] = *(const bf16x8*)&Blds[(wc + n * 16 + frow) * 32 + fk];
#pragma unroll
    for (int m = 0; m < 4; m++)
#pragma unroll
      for (int n = 0; n < 4; n++)
        acc[m][n] = __builtin_amdgcn_mfma_f32_16x16x32_bf16(af[m], bfv[n],
                                                            acc[m][n], 0, 0, 0);
    __syncthreads();
  }
  int rbase = row0 + wr + (lane >> 4) * 4;
  int cbase = col0 + wc + (lane & 15);
#pragma unroll
  for (int n = 0; n < 4; n++) {
    int ccol = cbase + n * 16;
    if (ccol >= N) continue;
    float bi = bias ? bias[ccol] : 0.f;
#pragma unroll
    for (int m = 0; m < 4; m++) {
      int r0_ = rbase + m * 16;
#pragma unroll
      for (int i = 0; i < 4; i++) {
        int r = r0_ + i;
        if (r < M) {
          size_t orow = r;
          if (rowmap) orow = (size_t)((r / KK) * TT + rowmap[r]);
          float v = acc[m][n][i] + bi;
          if (addmat) v += addmat[orow * ldc + ccol];
          C[orow * ldc + ccol] = v;
        }
      }
    }
  }
}

// ---------------- generic fp32 GEMM ----------------
__global__ __launch_bounds__(256) void gemm_f32(
    const float* __restrict__ A, int lda,
    const float* __restrict__ B, int ldb,
    float* __restrict__ C, int ldc,
    int M, int N, int Kd,
    const float* __restrict__ bias, int act) {
  __shared__ float As[16][65];
  __shared__ float Bs[16][65];
  int tx = threadIdx.x % 16;
  int ty = threadIdx.x / 16;
  int row0 = blockIdx.y * 64, col0 = blockIdx.x * 64;
  float acc[4][4] = {};
  int ar = threadIdx.x / 4;
  int ak = (threadIdx.x % 4) * 4;
  int bc = threadIdx.x % 64;
  int br = threadIdx.x / 64;
  for (int k0 = 0; k0 < Kd; k0 += 16) {
#pragma unroll
    for (int i = 0; i < 4; i++) {
      int gr = row0 + ar, gk = k0 + ak + i;
      float v = 0.f;
      if (gr < M && gk < Kd) v = A[(size_t)gr * lda + gk];
      As[ak + i][ar] = v;
    }
#pragma unroll
    for (int i = 0; i < 4; i++) {
      int gk = k0 + br + 4 * i, gc = col0 + bc;
      float v = 0.f;
      if (gk < Kd && gc < N) v = B[(size_t)gk * ldb + gc];
      Bs[br + 4 * i][bc] = v;
    }
    __syncthreads();
#pragma unroll
    for (int kk = 0; kk < 16; kk++) {
      float a[4], b[4];
#pragma unroll
      for (int i = 0; i < 4; i++) a[i] = As[kk][ty * 4 + i];
#pragma unroll
      for (int j = 0; j < 4; j++) b[j] = Bs[kk][tx * 4 + j];
#pragma unroll
      for (int i = 0; i < 4; i++)
#pragma unroll
        for (int j = 0; j < 4; j++) acc[i][j] += a[i] * b[j];
    }
    __syncthreads();
  }
#pragma unroll
  for (int i = 0; i < 4; i++) {
    int r = row0 + ty * 4 + i;
    if (r >= M) continue;
#pragma unroll
    for (int j = 0; j < 4; j++) {
      int c = col0 + tx * 4 + j;
      if (c >= N) continue;
      float v = acc[i][j];
      if (bias) v += bias[c];
      if (act == 1) v = fmaxf(v, 0.f);
      else if (act == 2) v = (v > 20.f) ? v : log1pf(__expf(v));
      C[(size_t)r * ldc + c] = v;
    }
  }
}

// ---------------- split-K fp32 GEMM: partial[ks] = A@B chunk ----------------
__global__ __launch_bounds__(256) void gemm_f32_splitk(
    const float* __restrict__ A, int lda,
    const float* __restrict__ B, int ldb,
    float* __restrict__ partial,  // [KSPL][M][N]
    int M, int N, int Kd) {
  __shared__ float As[16][65];
  __shared__ float Bs[16][65];
  int tx = threadIdx.x % 16;
  int ty = threadIdx.x / 16;
  int row0 = blockIdx.y * 64, col0 = blockIdx.x * 64;
  int ks = blockIdx.z;
  int kchunk = Kd / KSPL;
  int kbeg = ks * kchunk, kend = kbeg + kchunk;
  float acc[4][4] = {};
  int ar = threadIdx.x / 4;
  int ak = (threadIdx.x % 4) * 4;
  int bc = threadIdx.x % 64;
  int br = threadIdx.x / 64;
  for (int k0 = kbeg; k0 < kend; k0 += 16) {
#pragma unroll
    for (int i = 0; i < 4; i++) {
      int gr = row0 + ar, gk = k0 + ak + i;
      float v = 0.f;
      if (gr < M) v = A[(size_t)gr * lda + gk];
      As[ak + i][ar] = v;
    }
#pragma unroll
    for (int i = 0; i < 4; i++) {
      int gk = k0 + br + 4 * i, gc = col0 + bc;
      float v = 0.f;
      if (gc < N) v = B[(size_t)gk * ldb + gc];
      Bs[br + 4 * i][bc] = v;
    }
    __syncthreads();
#pragma unroll
    for (int kk = 0; kk < 16; kk++) {
      float a[4], b[4];
#pragma unroll
      for (int i = 0; i < 4; i++) a[i] = As[kk][ty * 4 + i];
#pragma unroll
      for (int j = 0; j < 4; j++) b[j] = Bs[kk][tx * 4 + j];
#pragma unroll
      for (int i = 0; i < 4; i++)
#pragma unroll
        for (int j = 0; j < 4; j++) acc[i][j] += a[i] * b[j];
    }
    __syncthreads();
  }
  float* P = partial + (size_t)ks * M * N;
#pragma unroll
  for (int i = 0; i < 4; i++) {
    int r = row0 + ty * 4 + i;
    if (r >= M) continue;
#pragma unroll
    for (int j = 0; j < 4; j++) {
      int c = col0 + tx * 4 + j;
      if (c < N) P[(size_t)r * N + c] = acc[i][j];
    }
  }
}

__global__ __launch_bounds__(256) void splitk_reduce(
    const float* __restrict__ partial, float* __restrict__ C, int MN, int act) {
  int i = blockIdx.x * 256 + threadIdx.x;
  if (i >= MN) return;
  float s = 0.f;
#pragma unroll
  for (int k = 0; k < KSPL; k++) s += partial[(size_t)k * MN + i];
  if (act == 1) s = fmaxf(s, 0.f);
  C[i] = s;
}

// ---------------- router score ----------------
__global__ __launch_bounds__(256) void router_score_kernel(
    const float* __restrict__ h, const float* __restrict__ Wr2,
    const float* __restrict__ br2, float* __restrict__ scores) {
  __shared__ float sh[4];
  int row = blockIdx.x;
  float v = h[(size_t)row * 256 + threadIdx.x] * Wr2[threadIdx.x];
  float s = block_sum256(v, sh);
  if (threadIdx.x == 0) scores[row] = s + br2[0];
}

// ---------------- exact top-K per batch (bitonic) ----------------
__global__ __launch_bounds__(1024) void topk_kernel(
    const float* __restrict__ scores, int* __restrict__ idx) {
  __shared__ float s[1024];
  __shared__ int si[1024];
  int b = blockIdx.x, t = threadIdx.x;
  s[t] = scores[b * TT + t];
  si[t] = t;
  __syncthreads();
  for (int k = 2; k <= 1024; k <<= 1) {
    for (int j = k >> 1; j > 0; j >>= 1) {
      int partner = t ^ j;
      if (partner > t) {
        bool dirDesc = ((t & k) == 0);
        float s1 = s[t], s2 = s[partner];
        int i1 = si[t], i2 = si[partner];
        bool firstGreater = (s1 > s2) || (s1 == s2 && i1 < i2);
        bool doSwap = dirDesc ? !firstGreater : firstGreater;
        if (doSwap) { s[t] = s2; s[partner] = s1; si[t] = i2; si[partner] = i1; }
      }
      __syncthreads();
    }
  }
  if (t < KK) idx[b * KK + t] = si[t];
}

// ---------------- causal conv (DC=4) + silu, 4 channels/thread ----------------
__global__ __launch_bounds__(256) void conv_silu_kernel(
    const float* __restrict__ uz, const float* __restrict__ conv_w,
    const float* __restrict__ conv_b, float* __restrict__ u) {
  size_t gid4 = ((size_t)blockIdx.x * 256 + threadIdx.x) * 4;  // over B*T*DI
  int c = gid4 % DII;
  size_t bt = gid4 / DII;
  int t = bt % TT;
  int b = bt / TT;
  f32x4 cw[4];
#pragma unroll
  for (int ci = 0; ci < 4; ci++) cw[ci] = *(const f32x4*)&conv_w[(c + ci) * DCC];
  f32x4 sum = *(const f32x4*)&conv_b[c];
#pragma unroll
  for (int j = 0; j < DCC; j++) {
    int tt = t - (DCC - 1) + j;
    if (tt >= 0) {
      f32x4 uv = *(const f32x4*)&uz[((size_t)(b * TT + tt)) * (2 * DII) + c];
#pragma unroll
      for (int ci = 0; ci < 4; ci++) sum[ci] += uv[ci] * cw[ci][j];
    }
  }
  f32x4 r;
#pragma unroll
  for (int ci = 0; ci < 4; ci++) r[ci] = sum[ci] / (1.f + __expf(-sum[ci]));
  *(f32x4*)&u[gid4] = r;
}

// ---------------- chunked selective scan (states in registers) ----------------
__global__ __launch_bounds__(256) void ssm_phase1(
    const float* __restrict__ dt, const float* __restrict__ proj,
    const float* __restrict__ u, const float* __restrict__ A_log,
    float* __restrict__ hloc, float* __restrict__ Pprod) {
  int gid = blockIdx.x * 256 + threadIdx.x;  // BB*NCH*DII
  int di = gid % DII;
  int rem = gid / DII;
  int chunk = rem % NCH;
  int b = rem / NCH;
  float a[DSS], h[DSS], P[DSS];
#pragma unroll
  for (int i = 0; i < 4; i++) {
    f32x4 al = *(const f32x4*)&A_log[di * DSS + i * 4];
#pragma unroll
    for (int j = 0; j < 4; j++) a[i * 4 + j] = -__expf(al[j]);
  }
#pragma unroll
  for (int s = 0; s < DSS; s++) { h[s] = 0.f; P[s] = 1.f; }
  int t0 = chunk * LCH;
  for (int lt = 0; lt < LCH; lt++) {
    size_t bt = (size_t)(b * TT + t0 + lt);
    float dtv = dt[bt * DII + di];
    float uv = u[bt * DII + di];
    const float* pr = proj + bt * 96 + DTRR;
    float dtu = dtv * uv;
#pragma unroll
    for (int s = 0; s < DSS; s++) {
      float dA = __expf(dtv * a[s]);
      h[s] = dA * h[s] + dtu * pr[s];
      P[s] *= dA;
    }
  }
#pragma unroll
  for (int i = 0; i < 4; i++) {
    *(f32x4*)&hloc[(size_t)gid * 16 + i * 4] = *(f32x4*)&h[i * 4];
    *(f32x4*)&Pprod[(size_t)gid * 16 + i * 4] = *(f32x4*)&P[i * 4];
  }
}

__global__ __launch_bounds__(256) void ssm_phase2(
    const float* __restrict__ hloc, const float* __restrict__ Pprod,
    float* __restrict__ hin) {
  int gid = blockIdx.x * 256 + threadIdx.x;  // BB*DII*16
  int s_di = gid % (DII * 16);
  int b = gid / (DII * 16);
  float run = 0.f;
#pragma unroll
  for (int c = 0; c < NCH; c++) {
    size_t off = ((size_t)(b * NCH + c) * DII) * 16 + s_di;
    hin[off] = run;
    run = Pprod[off] * run + hloc[off];
  }
}

__global__ __launch_bounds__(256) void ssm_phase3(
    const float* __restrict__ dt, const float* __restrict__ proj,
    const float* __restrict__ u, const float* __restrict__ uz,
    const float* __restrict__ A_log, const float* __restrict__ Dskip,
    const float* __restrict__ hin, __hip_bfloat16* __restrict__ y) {
  int gid = blockIdx.x * 256 + threadIdx.x;  // BB*NCH*DII
  int di = gid % DII;
  int rem = gid / DII;
  int chunk = rem % NCH;
  int b = rem / NCH;
  float a[DSS], h[DSS];
#pragma unroll
  for (int i = 0; i < 4; i++) {
    f32x4 al = *(const f32x4*)&A_log[di * DSS + i * 4];
    f32x4 hl = *(const f32x4*)&hin[(size_t)gid * 16 + i * 4];
#pragma unroll
    for (int j = 0; j < 4; j++) { a[i * 4 + j] = -__expf(al[j]); h[i * 4 + j] = hl[j]; }
  }
  float dsk = Dskip[di];
  int t0 = chunk * LCH;
  for (int lt = 0; lt < LCH; lt++) {
    size_t bt = (size_t)(b * TT + t0 + lt);
    float dtv = dt[bt * DII + di];
    float uv = u[bt * DII + di];
    float zv = uz[bt * (2 * DII) + DII + di];
    const float* pr = proj + bt * 96 + DTRR;
    float dtu = dtv * uv;
    float yp = 0.f;
#pragma unroll
    for (int s = 0; s < DSS; s++) {
      float dA = __expf(dtv * a[s]);
      h[s] = dA * h[s] + dtu * pr[s];
      yp += h[s] * pr[DSS + s];
    }
    float sz = zv / (1.f + __expf(-zv));
    y[bt * DII + di] = __float2bfloat16((yp + uv * dsk) * sz);
  }
}

// ---------------- gather selected tokens (bf16) ----------------
__global__ __launch_bounds__(256) void gather_tok(
    const __hip_bfloat16* __restrict__ xnb, const int* __restrict__ idx,
    __hip_bfloat16* __restrict__ tok) {
  int r = blockIdx.x;
  int b = r / KK;
  int tsel = idx[r];
  const __hip_bfloat16* src = xnb + ((size_t)(b * TT + tsel)) * DD;
  __hip_bfloat16* dst = tok + (size_t)r * DD;
#pragma unroll
  for (int j = 0; j < 4; j++) dst[threadIdx.x + 256 * j] = src[threadIdx.x + 256 * j];
}

// ---------------- MFMA attention: block per (b,h), 13 waves ----------------
#define KP 72
#define VP 232
__global__ __launch_bounds__(832) void attn_mfma_kernel(
    const float* __restrict__ qkv, __hip_bfloat16* __restrict__ attn_o) {
  __shared__ ushort Klds[208 * KP];        // 29952 B
  __shared__ ushort VTlds[64 * VP];        // 29696 B
  __shared__ ushort Plds[13 * 16 * VP];    // 96512 B  (total 152.5 KB)
  int bh = blockIdx.x;
  int h = bh % HH, b = bh / HH;
  int t = threadIdx.x;
  const float* base = qkv + (size_t)(b * KK) * 3072 + h * 64;

  for (int i = t; i < 208 * 64; i += 832) {
    int r = i >> 6, d = i & 63;
    float v = (r < KK) ? base[(size_t)r * 3072 + 1024 + d] : 0.f;
    Klds[r * KP + d] = f2bu(v);
  }
  for (int i = t; i < 208 * 64; i += 832) {
    int r = i >> 6, d = i & 63;
    float v = (r < KK) ? base[(size_t)r * 3072 + 2048 + d] : 0.f;
    VTlds[d * VP + r] = f2bu(v);
  }
  for (int i = t; i < 64 * (VP - 208); i += 832) {
    int d = i / (VP - 208), k = 208 + i % (VP - 208);
    VTlds[d * VP + k] = 0;
  }

  int wv = t >> 6, lane = t & 63;
  int q0 = wv * 16;
  int qrow = q0 + (lane & 15);
  if (qrow > KK - 1) qrow = KK - 1;
  const float* qptr = base + (size_t)qrow * 3072 + ((lane >> 4) * 8);
  bf16x8 qf[2];
#pragma unroll
  for (int ks = 0; ks < 2; ks++) {
    f32x4 lo = *(const f32x4*)(qptr + ks * 32);
    f32x4 hi = *(const f32x4*)(qptr + ks * 32 + 4);
#pragma unroll
    for (int j = 0; j < 4; j++) {
      qf[ks][j] = (short)f2bu(lo[j] * 0.125f);
      qf[ks][j + 4] = (short)f2bu(hi[j] * 0.125f);
    }
  }
  ushort* myP = Plds + wv * 16 * VP;
  for (int i = lane; i < 16 * (VP - 208); i += 64) {
    int r = i / (VP - 208), k = 208 + i % (VP - 208);
    myP[r * VP + k] = 0;
  }
  __syncthreads();

  f32x4 sacc[13] = {};
#pragma unroll
  for (int nt = 0; nt < 13; nt++) {
#pragma unroll
    for (int ks = 0; ks < 2; ks++) {
      bf16x8 kf = *(const bf16x8*)&Klds[(nt * 16 + (lane & 15)) * KP +
                                        ks * 32 + (lane >> 4) * 8];
      sacc[nt] = __builtin_amdgcn_mfma_f32_16x16x32_bf16(qf[ks], kf, sacc[nt], 0, 0, 0);
    }
  }
  if ((lane & 15) >= 12) {
#pragma unroll
    for (int i = 0; i < 4; i++) sacc[12][i] = -1e30f;
  }
  float m4[4], l4[4];
#pragma unroll
  for (int i = 0; i < 4; i++) {
    float m = sacc[0][i];
#pragma unroll
    for (int nt = 1; nt < 13; nt++) m = fmaxf(m, sacc[nt][i]);
    m = fmaxf(m, __shfl_xor(m, 1, 64));
    m = fmaxf(m, __shfl_xor(m, 2, 64));
    m = fmaxf(m, __shfl_xor(m, 4, 64));
    m = fmaxf(m, __shfl_xor(m, 8, 64));
    m4[i] = m;
  }
#pragma unroll
  for (int i = 0; i < 4; i++) {
    float ls = 0.f;
    int prow = (lane >> 4) * 4 + i;
#pragma unroll
    for (int nt = 0; nt < 13; nt++) {
      float e = __expf(sacc[nt][i] - m4[i]);
      ls += e;
      myP[prow * VP + nt * 16 + (lane & 15)] = f2bu(e);
    }
    ls += __shfl_xor(ls, 1, 64);
    ls += __shfl_xor(ls, 2, 64);
    ls += __shfl_xor(ls, 4, 64);
    ls += __shfl_xor(ls, 8, 64);
    l4[i] = ls;
  }
  f32x4 oacc[4] = {};
#pragma unroll
  for (int dt = 0; dt < 4; dt++) {
#pragma unroll
    for (int ks = 0; ks < 7; ks++) {
      bf16x8 pf = *(const bf16x8*)&myP[(lane & 15) * VP + ks * 32 + (lane >> 4) * 8];
      bf16x8 vf = *(const bf16x8*)&VTlds[(dt * 16 + (lane & 15)) * VP +
                                         ks * 32 + (lane >> 4) * 8];
      oacc[dt] = __builtin_amdgcn_mfma_f32_16x16x32_bf16(pf, vf, oacc[dt], 0, 0, 0);
    }
  }
#pragma unroll
  for (int i = 0; i < 4; i++) {
    int row = q0 + (lane >> 4) * 4 + i;
    if (row >= KK) continue;
    float inv = 1.f / l4[i];
#pragma unroll
    for (int dt = 0; dt < 4; dt++) {
      int col = dt * 16 + (lane & 15);
      attn_o[((size_t)(b * KK + row)) * DD + h * 64 + col] =
          __float2bfloat16(oacc[dt][i] * inv);
    }
  }
}

extern "C" void kernel_launch(void* const* d_in, const int* in_sizes, int n_in,
                              void* d_out, int out_size, void* d_ws, size_t ws_size,
                              hipStream_t stream) {
  const float* x = (const float*)d_in[0];
  const float* ln_g = (const float*)d_in[1];
  const float* ln_b = (const float*)d_in[2];
  const float* Wr1 = (const float*)d_in[3];
  const float* br1 = (const float*)d_in[4];
  const float* Wr2 = (const float*)d_in[5];
  const float* br2 = (const float*)d_in[6];
  const float* Wqkv = (const float*)d_in[7];
  const float* bqkv = (const float*)d_in[8];
  const float* Wo = (const float*)d_in[9];
  const float* bo = (const float*)d_in[10];
  const float* W_in = (const float*)d_in[11];
  const float* conv_w = (const float*)d_in[12];
  const float* conv_b = (const float*)d_in[13];
  const float* W_xproj = (const float*)d_in[14];
  const float* W_dt = (const float*)d_in[15];
  const float* b_dt = (const float*)d_in[16];
  const float* A_log = (const float*)d_in[17];
  const float* Dskip = (const float*)d_in[18];
  const float* W_out = (const float*)d_in[19];
  float* out = (float*)d_out;

  float* w = (float*)d_ws;
  size_t o = 0;
  float* xn = w + o;     o += (size_t)BB * TT * DD;
  float* hbuf = w + o;   o += (size_t)BB * TT * 256;
  float* scores = w + o; o += (size_t)BB * TT;
  int* idxb = (int*)(w + o); o += 1024;
  float* uzb = w + o;    o += (size_t)BB * TT * 2 * DII;
  float* ub = w + o;     o += (size_t)BB * TT * DII;
  float* projb = w + o;  o += (size_t)BB * TT * 96;
  float* dtb = w + o;    o += (size_t)BB * TT * DII;
  float* qkvb = w + o;   o += (size_t)BB * KK * 3 * DD;
  float* hloc = w + o;   o += (size_t)BB * NCH * DII * 16;
  float* Pprod = w + o;  o += (size_t)BB * NCH * DII * 16;
  float* hin = w + o;    o += (size_t)BB * NCH * DII * 16;
  __hip_bfloat16* xnb = (__hip_bfloat16*)(w + o);   o += (size_t)BB * TT * DD / 2;
  __hip_bfloat16* yb16 = (__hip_bfloat16*)(w + o);  o += (size_t)BB * TT * DII / 2;
  __hip_bfloat16* tokb = (__hip_bfloat16*)(w + o);  o += (size_t)BB * KK * DD / 2 + 8;
  __hip_bfloat16* attno = (__hip_bfloat16*)(w + o); o += (size_t)BB * KK * DD / 2 + 8;
  __hip_bfloat16* WinT = (__hip_bfloat16*)(w + o);  o += (size_t)(2 * DII) * DD / 2;
  __hip_bfloat16* WoutT = (__hip_bfloat16*)(w + o); o += (size_t)DD * DII / 2;
  __hip_bfloat16* WqkvT = (__hip_bfloat16*)(w + o); o += (size_t)(3 * DD) * DD / 2;
  __hip_bfloat16* WoT = (__hip_bfloat16*)(w + o);   o += (size_t)DD * DD / 2;
  // overlays: router partials -> uzb (33.55 MB, dead until W_in GEMM);
  // xproj partials -> hloc (16.8 MB >= 12.6 MB, dead until ssm_phase1).
  float* rpart = uzb;
  float* xpart = hloc;

  // 1. layernorm
  layernorm_kernel<<<BB * TT, 256, 0, stream>>>(x, ln_g, ln_b, xn, xnb);
  // weight transposes/converts (bf16 [N,K])
  transpose_bf16<<<dim3(2 * DII / 32, DD / 32), 256, 0, stream>>>(W_in, DD, 2 * DII, WinT);
  transpose_bf16<<<dim3(DD / 32, DII / 32), 256, 0, stream>>>(W_out, DII, DD, WoutT);
  transpose_bf16<<<dim3(3 * DD / 32, DD / 32), 256, 0, stream>>>(Wqkv, DD, 3 * DD, WqkvT);
  transpose_bf16<<<dim3(DD / 32, DD / 32), 256, 0, stream>>>(Wo, DD, DD, WoT);
  // 2. router (fp32 split-K; selection bit-exact)
  gemm_f32_splitk<<<dim3(4, 64, KSPL), 256, 0, stream>>>(
      xn, DD, Wr1, 256, rpart, BB * TT, 256, DD);
  splitk_reduce<<<(BB * TT * 256 + 255) / 256, 256, 0, stream>>>(
      rpart, hbuf, BB * TT * 256, 1);
  router_score_kernel<<<BB * TT, 256, 0, stream>>>(hbuf, Wr2, br2, scores);
  topk_kernel<<<BB, 1024, 0, stream>>>(scores, idxb);
  // 3. SSM branch: uz (256 MFMA) -> conv -> xproj -> dt -> scan -> W_out
  gemm_bf16_256<<<dim3(2 * DII / 256, BB * TT / 256), 512, 0, stream>>>(
      (const ushort*)xnb, DD, (const ushort*)WinT, DD, uzb, 2 * DII, DD,
      nullptr, nullptr);
  conv_silu_kernel<<<(BB * TT * DII) / 1024, 256, 0, stream>>>(uzb, conv_w, conv_b, ub);
  gemm_f32_splitk<<<dim3(2, 64, KSPL), 256, 0, stream>>>(
      ub, DII, W_xproj, XPN, xpart, BB * TT, XPN, DII);
  splitk_reduce<<<(BB * TT * XPN + 255) / 256, 256, 0, stream>>>(
      xpart, projb, BB * TT * XPN, 0);
  gemm_f32<<<dim3(32, 64), 256, 0, stream>>>(projb, 96, W_dt, DII, dtb, DII,
                                             BB * TT, DII, DTRR, b_dt, 2);
  ssm_phase1<<<(BB * NCH * DII) / 256, 256, 0, stream>>>(dtb, projb, ub, A_log,
                                                         hloc, Pprod);
  ssm_phase2<<<(BB * DII * 16) / 256, 256, 0, stream>>>(hloc, Pprod, hin);
  ssm_phase3<<<(BB * NCH * DII) / 256, 256, 0, stream>>>(dtb, projb, ub, uzb,
                                                         A_log, Dskip, hin, yb16);
  // out = y@W_out + x (256 MFMA, fused residual)
  gemm_bf16_256<<<dim3(DD / 256, BB * TT / 256), 512, 0, stream>>>(
      (const ushort*)yb16, DII, (const ushort*)WoutT, DII, out, DD, DII,
      nullptr, x);
  // 4. attention branch
  gather_tok<<<BB * KK, 256, 0, stream>>>(xnb, idxb, tokb);
  gemm_bf16_mfma<<<dim3(3 * DD / 128, (BB * KK + 127) / 128), 256, 0, stream>>>(
      (const ushort*)tokb, DD, (const ushort*)WqkvT, DD, qkvb, 3 * DD,
      BB * KK, 3 * DD, DD, bqkv, nullptr, nullptr);
  attn_mfma_kernel<<<BB * HH, 832, 0, stream>>>(qkvb, attno);
  // Wo MFMA with fused scatter: out[b, idx[r], :] = acc + bo + x[...]
  gemm_bf16_mfma<<<dim3(DD / 128, (BB * KK + 127) / 128), 256, 0, stream>>>(
      (const ushort*)attno, DD, (const ushort*)WoT, DD, out, DD,
      BB * KK, DD, DD, bo, x, idxb);
}

// Round 10
// 593.079 us; speedup vs baseline: 1.1336x; 1.1336x over previous
//
#include <hip/hip_runtime.h>
#include <hip/hip_bf16.h>
#include <math.h>

#define BB   4
#define TT   1024
#define DD   1024
#define HH   16
#define DII  2048
#define DSS  16
#define DCC  4
#define KK   204
#define HDD  64
#define DTRR 64
#define NCH  32
#define LCH  32    // TT / NCH
#define KSPL 8
#define XPN  96
#define WKSP 4     // split-K factor for W_out 256 GEMM

typedef short bf16x8 __attribute__((ext_vector_type(8)));
typedef float f32x4 __attribute__((ext_vector_type(4)));

#define GLDS16(g, l) __builtin_amdgcn_global_load_lds(                        \
    (const __attribute__((address_space(1))) void*)(g),                       \
    (__attribute__((address_space(3))) void*)(l), 16, 0, 0)

__device__ __forceinline__ ushort f2bu(float v) {
  __hip_bfloat16 h = __float2bfloat16(v);
  return __builtin_bit_cast(ushort, h);
}

// ---------------- reduction helpers ----------------
__device__ __forceinline__ float wave_sum(float v) {
#pragma unroll
  for (int o = 32; o > 0; o >>= 1) v += __shfl_xor(v, o, 64);
  return v;
}
__device__ __forceinline__ float block_sum256(float v, volatile float* sh) {
  v = wave_sum(v);
  if ((threadIdx.x & 63) == 0) sh[threadIdx.x >> 6] = v;
  __syncthreads();
  float r = sh[0] + sh[1] + sh[2] + sh[3];
  __syncthreads();
  return r;
}

// ---------------- layernorm (writes fp32 + bf16) ----------------
__global__ __launch_bounds__(256) void layernorm_kernel(
    const float* __restrict__ x, const float* __restrict__ g,
    const float* __restrict__ be, float* __restrict__ xn,
    __hip_bfloat16* __restrict__ xnb) {
  __shared__ float sh[4];
  int row = blockIdx.x;
  const float* xr = x + (size_t)row * DD;
  float v[4];
  float s = 0.f;
#pragma unroll
  for (int i = 0; i < 4; i++) { v[i] = xr[threadIdx.x + 256 * i]; s += v[i]; }
  float mean = block_sum256(s, sh) * (1.f / DD);
  float q = 0.f;
#pragma unroll
  for (int i = 0; i < 4; i++) { float d = v[i] - mean; q += d * d; }
  float var = block_sum256(q, sh) * (1.f / DD);
  float rstd = rsqrtf(var + 1e-5f);
#pragma unroll
  for (int i = 0; i < 4; i++) {
    int c = threadIdx.x + 256 * i;
    float o = (v[i] - mean) * rstd * g[c] + be[c];
    xn[(size_t)row * DD + c] = o;
    xnb[(size_t)row * DD + c] = __float2bfloat16(o);
  }
}

// ---------------- transpose + convert: W[rows,cols] f32 -> WT[cols,rows] bf16 ----
__global__ __launch_bounds__(256) void transpose_bf16(
    const float* __restrict__ W, int rows, int cols,
    __hip_bfloat16* __restrict__ WT) {
  __shared__ float tile[32][33];
  int c0 = blockIdx.x * 32, r0 = blockIdx.y * 32;
  int tx = threadIdx.x & 31, ty = threadIdx.x >> 5;
#pragma unroll
  for (int i = 0; i < 32; i += 8)
    tile[ty + i][tx] = W[(size_t)(r0 + ty + i) * cols + c0 + tx];
  __syncthreads();
#pragma unroll
  for (int i = 0; i < 32; i += 8)
    WT[(size_t)(c0 + ty + i) * rows + r0 + tx] = __float2bfloat16(tile[tx][ty + i]);
}

// ---------------- 256x256 2-phase bf16 MFMA GEMM (M,N %256, K %64) ----------
// C[M,N] fp32 = A@BT^T (+bias, +addmat). 512 thr, 8 waves (2Mx4N),
// wave tile 128x64, BK=64, linear LDS + global_load_lds, XCD swizzle.
__global__ __launch_bounds__(512) void gemm_bf16_256(
    const ushort* __restrict__ A, int lda,
    const ushort* __restrict__ BT, int ldbt,
    float* __restrict__ C, int ldc, int K,
    const float* __restrict__ bias, const float* __restrict__ addmat) {
  __shared__ ushort Alds[256 * 64];   // 32 KB
  __shared__ ushort Blds[256 * 64];   // 32 KB
  int t = threadIdx.x;
  int wv = t >> 6, lane = t & 63;
  int wvm = wv >> 2, wvn = wv & 3;
  int nwg = gridDim.x * gridDim.y;
  int lin = blockIdx.y * gridDim.x + blockIdx.x;
  int swz = (lin & 7) * (nwg >> 3) + (lin >> 3);
  int bx = swz % gridDim.x, by = swz / gridDim.x;
  int row0 = by * 256, col0 = bx * 256;
  f32x4 acc[8][4] = {};

  const ushort* Ap[4];
  const ushort* Bp[4];
  ushort* Alb[4];
  ushort* Blb[4];
#pragma unroll
  for (int j = 0; j < 4; j++) {
    int c = j * 512 + t;
    int r = c >> 3, kc = (c & 7) * 8;
    Ap[j] = A + (size_t)(row0 + r) * lda + kc;
    Bp[j] = BT + (size_t)(col0 + r) * ldbt + kc;
    int cst = j * 512 + wv * 64;          // wave-uniform chunk base
    Alb[j] = Alds + (size_t)cst * 8;
    Blb[j] = Blds + (size_t)cst * 8;
  }
  int frow = lane & 15, fk = (lane >> 4) * 8;

  for (int k0 = 0; k0 < K; k0 += 64) {
#pragma unroll
    for (int j = 0; j < 4; j++) {
      GLDS16(Ap[j] + k0, Alb[j]);
      GLDS16(Bp[j] + k0, Blb[j]);
    }
    __syncthreads();
#pragma unroll
    for (int ks = 0; ks < 2; ks++) {
      bf16x8 af[8], bfv[4];
#pragma unroll
      for (int m = 0; m < 8; m++)
        af[m] = *(const bf16x8*)&Alds[(wvm * 128 + m * 16 + frow) * 64 +
                                      ks * 32 + fk];
#pragma unroll
      for (int n = 0; n < 4; n++)
        bfv[n] = *(const bf16x8*)&Blds[(wvn * 64 + n * 16 + frow) * 64 +
                                       ks * 32 + fk];
#pragma unroll
      for (int m = 0; m < 8; m++)
#pragma unroll
        for (int n = 0; n < 4; n++)
          acc[m][n] = __builtin_amdgcn_mfma_f32_16x16x32_bf16(af[m], bfv[n],
                                                              acc[m][n], 0, 0, 0);
    }
    __syncthreads();
  }
  int rbase = row0 + wvm * 128 + (lane >> 4) * 4;
  int cbase = col0 + wvn * 64 + (lane & 15);
#pragma unroll
  for (int n = 0; n < 4; n++) {
    int cc = cbase + n * 16;
    float bi = bias ? bias[cc] : 0.f;
#pragma unroll
    for (int m = 0; m < 8; m++) {
#pragma unroll
      for (int i = 0; i < 4; i++) {
        size_t r = rbase + m * 16 + i;
        float v = acc[m][n][i] + bi;
        if (addmat) v += addmat[r * ldc + cc];
        C[r * ldc + cc] = v;
      }
    }
  }
}

// ---------------- 256x256 split-K variant: partial[z] = A@BT^T (K chunk) ----
__global__ __launch_bounds__(512) void gemm_bf16_256_splitk(
    const ushort* __restrict__ A, int lda,
    const ushort* __restrict__ BT, int ldbt,
    float* __restrict__ partial, int ldc, int Ktot, size_t zstride) {
  __shared__ ushort Alds[256 * 64];
  __shared__ ushort Blds[256 * 64];
  int t = threadIdx.x;
  int wv = t >> 6, lane = t & 63;
  int wvm = wv >> 2, wvn = wv & 3;
  int nwg = gridDim.x * gridDim.y;
  int lin = blockIdx.y * gridDim.x + blockIdx.x;
  int swz = (lin & 7) * (nwg >> 3) + (lin >> 3);
  int bx = swz % gridDim.x, by = swz / gridDim.x;
  int row0 = by * 256, col0 = bx * 256;
  int kchunk = Ktot / WKSP;
  int kbeg = blockIdx.z * kchunk, kend = kbeg + kchunk;
  f32x4 acc[8][4] = {};

  const ushort* Ap[4];
  const ushort* Bp[4];
  ushort* Alb[4];
  ushort* Blb[4];
#pragma unroll
  for (int j = 0; j < 4; j++) {
    int c = j * 512 + t;
    int r = c >> 3, kc = (c & 7) * 8;
    Ap[j] = A + (size_t)(row0 + r) * lda + kc;
    Bp[j] = BT + (size_t)(col0 + r) * ldbt + kc;
    int cst = j * 512 + wv * 64;
    Alb[j] = Alds + (size_t)cst * 8;
    Blb[j] = Blds + (size_t)cst * 8;
  }
  int frow = lane & 15, fk = (lane >> 4) * 8;

  for (int k0 = kbeg; k0 < kend; k0 += 64) {
#pragma unroll
    for (int j = 0; j < 4; j++) {
      GLDS16(Ap[j] + k0, Alb[j]);
      GLDS16(Bp[j] + k0, Blb[j]);
    }
    __syncthreads();
#pragma unroll
    for (int ks = 0; ks < 2; ks++) {
      bf16x8 af[8], bfv[4];
#pragma unroll
      for (int m = 0; m < 8; m++)
        af[m] = *(const bf16x8*)&Alds[(wvm * 128 + m * 16 + frow) * 64 +
                                      ks * 32 + fk];
#pragma unroll
      for (int n = 0; n < 4; n++)
        bfv[n] = *(const bf16x8*)&Blds[(wvn * 64 + n * 16 + frow) * 64 +
                                       ks * 32 + fk];
#pragma unroll
      for (int m = 0; m < 8; m++)
#pragma unroll
        for (int n = 0; n < 4; n++)
          acc[m][n] = __builtin_amdgcn_mfma_f32_16x16x32_bf16(af[m], bfv[n],
                                                              acc[m][n], 0, 0, 0);
    }
    __syncthreads();
  }
  float* P = partial + (size_t)blockIdx.z * zstride;
  int rbase = row0 + wvm * 128 + (lane >> 4) * 4;
  int cbase = col0 + wvn * 64 + (lane & 15);
#pragma unroll
  for (int n = 0; n < 4; n++) {
    int cc = cbase + n * 16;
#pragma unroll
    for (int m = 0; m < 8; m++)
#pragma unroll
      for (int i = 0; i < 4; i++)
        P[(size_t)(rbase + m * 16 + i) * ldc + cc] = acc[m][n][i];
  }
}

// out = sum_z partial[z] + x  (vectorized f32x4, fixed z order)
__global__ __launch_bounds__(256) void splitk4_add_reduce(
    const float* __restrict__ partial, const float* __restrict__ x,
    float* __restrict__ out, size_t zstride) {
  size_t i = ((size_t)blockIdx.x * 256 + threadIdx.x) * 4;
  f32x4 s = *(const f32x4*)&partial[i];
#pragma unroll
  for (int z = 1; z < WKSP; z++) {
    f32x4 p = *(const f32x4*)&partial[z * zstride + i];
#pragma unroll
    for (int j = 0; j < 4; j++) s[j] += p[j];
  }
  f32x4 xv = *(const f32x4*)&x[i];
#pragma unroll
  for (int j = 0; j < 4; j++) s[j] += xv[j];
  *(f32x4*)&out[i] = s;
}

// ---------------- 128x128 bf16 MFMA GEMM (fp32 C) ----------------
// C[M,N] = A[M,K] @ BT[N,K]^T + bias (+addmat). rowmap: out row r ->
// (r/KK)*TT + rowmap[r] (fused top-K scatter). XCD swizzle (nwg %8==0).
__global__ __launch_bounds__(256) void gemm_bf16_mfma(
    const ushort* __restrict__ A, int lda,
    const ushort* __restrict__ BT, int ldbt,
    float* __restrict__ C, int ldc,
    int M, int N, int K, const float* __restrict__ bias,
    const float* __restrict__ addmat, const int* __restrict__ rowmap) {
  __shared__ ushort Alds[128 * 32];
  __shared__ ushort Blds[128 * 32];
  int t = threadIdx.x;
  int wv = t >> 6;
  int lane = t & 63;
  int nwg = gridDim.x * gridDim.y;
  int lin = blockIdx.y * gridDim.x + blockIdx.x;
  int swz = (lin & 7) * (nwg >> 3) + (lin >> 3);
  int bx = swz % gridDim.x, by = swz / gridDim.x;
  int row0 = by * 128, col0 = bx * 128;
  int wr = (wv >> 1) * 64, wc = (wv & 1) * 64;
  f32x4 acc[4][4] = {};

  int srow = t >> 2;
  int sk = (t & 3) * 8;
  int ar0 = row0 + srow;       if (ar0 >= M) ar0 = M - 1;
  int ar1 = row0 + 64 + srow;  if (ar1 >= M) ar1 = M - 1;
  int br0 = col0 + srow;       if (br0 >= N) br0 = N - 1;
  int br1 = col0 + 64 + srow;  if (br1 >= N) br1 = N - 1;
  const ushort* Ag0 = A + (size_t)ar0 * lda + sk;
  const ushort* Ag1 = A + (size_t)ar1 * lda + sk;
  const ushort* Bg0 = BT + (size_t)br0 * ldbt + sk;
  const ushort* Bg1 = BT + (size_t)br1 * ldbt + sk;
  ushort* Al = Alds + wv * 512;
  ushort* Bl = Blds + wv * 512;

  int frow = lane & 15;
  int fk = (lane >> 4) * 8;

  for (int k0 = 0; k0 < K; k0 += 32) {
    GLDS16(Ag0 + k0, Al);
    GLDS16(Ag1 + k0, Al + 2048);
    GLDS16(Bg0 + k0, Bl);
    GLDS16(Bg1 + k0, Bl + 2048);
    __syncthreads();
    bf16x8 af[4], bfv[4];
#pragma unroll
    for (int m = 0; m < 4; m++)
      af[m] = *(const bf16x8*)&Alds[(wr + m * 16 + frow) * 32 + fk];
#pragma unroll
    for (int n = 0; n < 4; n++)
      bfv[n] = *(const bf16x8*)&Blds[(wc + n * 16 + frow) * 32 + fk];
#pragma unroll
    for (int m = 0; m < 4; m++)
#pragma unroll
      for (int n = 0; n < 4; n++)
        acc[m][n] = __builtin_amdgcn_mfma_f32_16x16x32_bf16(af[m], bfv[n],
                                                            acc[m][n], 0, 0, 0);
    __syncthreads();
  }
  int rbase = row0 + wr + (lane >> 4) * 4;
  int cbase = col0 + wc + (lane & 15);
#pragma unroll
  for (int n = 0; n < 4; n++) {
    int ccol = cbase + n * 16;
    if (ccol >= N) continue;
    float bi = bias ? bias[ccol] : 0.f;
#pragma unroll
    for (int m = 0; m < 4; m++) {
      int r0_ = rbase + m * 16;
#pragma unroll
      for (int i = 0; i < 4; i++) {
        int r = r0_ + i;
        if (r < M) {
          size_t orow = r;
          if (rowmap) orow = (size_t)((r / KK) * TT + rowmap[r]);
          float v = acc[m][n][i] + bi;
          if (addmat) v += addmat[orow * ldc + ccol];
          C[orow * ldc + ccol] = v;
        }
      }
    }
  }
}

// ---------------- generic fp32 GEMM ----------------
__global__ __launch_bounds__(256) void gemm_f32(
    const float* __restrict__ A, int lda,
    const float* __restrict__ B, int ldb,
    float* __restrict__ C, int ldc,
    int M, int N, int Kd,
    const float* __restrict__ bias, int act) {
  __shared__ float As[16][65];
  __shared__ float Bs[16][65];
  int tx = threadIdx.x % 16;
  int ty = threadIdx.x / 16;
  int row0 = blockIdx.y * 64, col0 = blockIdx.x * 64;
  float acc[4][4] = {};
  int ar = threadIdx.x / 4;
  int ak = (threadIdx.x % 4) * 4;
  int bc = threadIdx.x % 64;
  int br = threadIdx.x / 64;
  for (int k0 = 0; k0 < Kd; k0 += 16) {
#pragma unroll
    for (int i = 0; i < 4; i++) {
      int gr = row0 + ar, gk = k0 + ak + i;
      float v = 0.f;
      if (gr < M && gk < Kd) v = A[(size_t)gr * lda + gk];
      As[ak + i][ar] = v;
    }
#pragma unroll
    for (int i = 0; i < 4; i++) {
      int gk = k0 + br + 4 * i, gc = col0 + bc;
      float v = 0.f;
      if (gk < Kd && gc < N) v = B[(size_t)gk * ldb + gc];
      Bs[br + 4 * i][bc] = v;
    }
    __syncthreads();
#pragma unroll
    for (int kk = 0; kk < 16; kk++) {
      float a[4], b[4];
#pragma unroll
      for (int i = 0; i < 4; i++) a[i] = As[kk][ty * 4 + i];
#pragma unroll
      for (int j = 0; j < 4; j++) b[j] = Bs[kk][tx * 4 + j];
#pragma unroll
      for (int i = 0; i < 4; i++)
#pragma unroll
        for (int j = 0; j < 4; j++) acc[i][j] += a[i] * b[j];
    }
    __syncthreads();
  }
#pragma unroll
  for (int i = 0; i < 4; i++) {
    int r = row0 + ty * 4 + i;
    if (r >= M) continue;
#pragma unroll
    for (int j = 0; j < 4; j++) {
      int c = col0 + tx * 4 + j;
      if (c >= N) continue;
      float v = acc[i][j];
      if (bias) v += bias[c];
      if (act == 1) v = fmaxf(v, 0.f);
      else if (act == 2) v = (v > 20.f) ? v : log1pf(__expf(v));
      C[(size_t)r * ldc + c] = v;
    }
  }
}

// ---------------- split-K fp32 GEMM: partial[ks] = A@B chunk ----------------
__global__ __launch_bounds__(256) void gemm_f32_splitk(
    const float* __restrict__ A, int lda,
    const float* __restrict__ B, int ldb,
    float* __restrict__ partial,  // [KSPL][M][N]
    int M, int N, int Kd) {
  __shared__ float As[16][65];
  __shared__ float Bs[16][65];
  int tx = threadIdx.x % 16;
  int ty = threadIdx.x / 16;
  int row0 = blockIdx.y * 64, col0 = blockIdx.x * 64;
  int ks = blockIdx.z;
  int kchunk = Kd / KSPL;
  int kbeg = ks * kchunk, kend = kbeg + kchunk;
  float acc[4][4] = {};
  int ar = threadIdx.x / 4;
  int ak = (threadIdx.x % 4) * 4;
  int bc = threadIdx.x % 64;
  int br = threadIdx.x / 64;
  for (int k0 = kbeg; k0 < kend; k0 += 16) {
#pragma unroll
    for (int i = 0; i < 4; i++) {
      int gr = row0 + ar, gk = k0 + ak + i;
      float v = 0.f;
      if (gr < M) v = A[(size_t)gr * lda + gk];
      As[ak + i][ar] = v;
    }
#pragma unroll
    for (int i = 0; i < 4; i++) {
      int gk = k0 + br + 4 * i, gc = col0 + bc;
      float v = 0.f;
      if (gc < N) v = B[(size_t)gk * ldb + gc];
      Bs[br + 4 * i][bc] = v;
    }
    __syncthreads();
#pragma unroll
    for (int kk = 0; kk < 16; kk++) {
      float a[4], b[4];
#pragma unroll
      for (int i = 0; i < 4; i++) a[i] = As[kk][ty * 4 + i];
#pragma unroll
      for (int j = 0; j < 4; j++) b[j] = Bs[kk][tx * 4 + j];
#pragma unroll
      for (int i = 0; i < 4; i++)
#pragma unroll
        for (int j = 0; j < 4; j++) acc[i][j] += a[i] * b[j];
    }
    __syncthreads();
  }
  float* P = partial + (size_t)ks * M * N;
#pragma unroll
  for (int i = 0; i < 4; i++) {
    int r = row0 + ty * 4 + i;
    if (r >= M) continue;
#pragma unroll
    for (int j = 0; j < 4; j++) {
      int c = col0 + tx * 4 + j;
      if (c < N) P[(size_t)r * N + c] = acc[i][j];
    }
  }
}

__global__ __launch_bounds__(256) void splitk_reduce(
    const float* __restrict__ partial, float* __restrict__ C, int MN, int act) {
  int i = blockIdx.x * 256 + threadIdx.x;
  if (i >= MN) return;
  float s = 0.f;
#pragma unroll
  for (int k = 0; k < KSPL; k++) s += partial[(size_t)k * MN + i];
  if (act == 1) s = fmaxf(s, 0.f);
  C[i] = s;
}

// ---------------- router score ----------------
__global__ __launch_bounds__(256) void router_score_kernel(
    const float* __restrict__ h, const float* __restrict__ Wr2,
    const float* __restrict__ br2, float* __restrict__ scores) {
  __shared__ float sh[4];
  int row = blockIdx.x;
  float v = h[(size_t)row * 256 + threadIdx.x] * Wr2[threadIdx.x];
  float s = block_sum256(v, sh);
  if (threadIdx.x == 0) scores[row] = s + br2[0];
}

// ---------------- exact top-K per batch (bitonic) ----------------
__global__ __launch_bounds__(1024) void topk_kernel(
    const float* __restrict__ scores, int* __restrict__ idx) {
  __shared__ float s[1024];
  __shared__ int si[1024];
  int b = blockIdx.x, t = threadIdx.x;
  s[t] = scores[b * TT + t];
  si[t] = t;
  __syncthreads();
  for (int k = 2; k <= 1024; k <<= 1) {
    for (int j = k >> 1; j > 0; j >>= 1) {
      int partner = t ^ j;
      if (partner > t) {
        bool dirDesc = ((t & k) == 0);
        float s1 = s[t], s2 = s[partner];
        int i1 = si[t], i2 = si[partner];
        bool firstGreater = (s1 > s2) || (s1 == s2 && i1 < i2);
        bool doSwap = dirDesc ? !firstGreater : firstGreater;
        if (doSwap) { s[t] = s2; s[partner] = s1; si[t] = i2; si[partner] = i1; }
      }
      __syncthreads();
    }
  }
  if (t < KK) idx[b * KK + t] = si[t];
}

// ---------------- causal conv (DC=4) + silu, 4 channels/thread ----------------
__global__ __launch_bounds__(256) void conv_silu_kernel(
    const float* __restrict__ uz, const float* __restrict__ conv_w,
    const float* __restrict__ conv_b, float* __restrict__ u) {
  size_t gid4 = ((size_t)blockIdx.x * 256 + threadIdx.x) * 4;  // over B*T*DI
  int c = gid4 % DII;
  size_t bt = gid4 / DII;
  int t = bt % TT;
  int b = bt / TT;
  f32x4 cw[4];
#pragma unroll
  for (int ci = 0; ci < 4; ci++) cw[ci] = *(const f32x4*)&conv_w[(c + ci) * DCC];
  f32x4 sum = *(const f32x4*)&conv_b[c];
#pragma unroll
  for (int j = 0; j < DCC; j++) {
    int tt = t - (DCC - 1) + j;
    if (tt >= 0) {
      f32x4 uv = *(const f32x4*)&uz[((size_t)(b * TT + tt)) * (2 * DII) + c];
#pragma unroll
      for (int ci = 0; ci < 4; ci++) sum[ci] += uv[ci] * cw[ci][j];
    }
  }
  f32x4 r;
#pragma unroll
  for (int ci = 0; ci < 4; ci++) r[ci] = sum[ci] / (1.f + __expf(-sum[ci]));
  *(f32x4*)&u[gid4] = r;
}

// ---------------- chunked selective scan (states in registers) ----------------
__global__ __launch_bounds__(256) void ssm_phase1(
    const float* __restrict__ dt, const float* __restrict__ proj,
    const float* __restrict__ u, const float* __restrict__ A_log,
    float* __restrict__ hloc, float* __restrict__ Pprod) {
  int gid = blockIdx.x * 256 + threadIdx.x;  // BB*NCH*DII
  int di = gid % DII;
  int rem = gid / DII;
  int chunk = rem % NCH;
  int b = rem / NCH;
  float a[DSS], h[DSS], P[DSS];
#pragma unroll
  for (int i = 0; i < 4; i++) {
    f32x4 al = *(const f32x4*)&A_log[di * DSS + i * 4];
#pragma unroll
    for (int j = 0; j < 4; j++) a[i * 4 + j] = -__expf(al[j]);
  }
#pragma unroll
  for (int s = 0; s < DSS; s++) { h[s] = 0.f; P[s] = 1.f; }
  int t0 = chunk * LCH;
  for (int lt = 0; lt < LCH; lt++) {
    size_t bt = (size_t)(b * TT + t0 + lt);
    float dtv = dt[bt * DII + di];
    float uv = u[bt * DII + di];
    const float* pr = proj + bt * 96 + DTRR;
    float dtu = dtv * uv;
#pragma unroll
    for (int s = 0; s < DSS; s++) {
      float dA = __expf(dtv * a[s]);
      h[s] = dA * h[s] + dtu * pr[s];
      P[s] *= dA;
    }
  }
#pragma unroll
  for (int i = 0; i < 4; i++) {
    *(f32x4*)&hloc[(size_t)gid * 16 + i * 4] = *(f32x4*)&h[i * 4];
    *(f32x4*)&Pprod[(size_t)gid * 16 + i * 4] = *(f32x4*)&P[i * 4];
  }
}

__global__ __launch_bounds__(256) void ssm_phase2(
    const float* __restrict__ hloc, const float* __restrict__ Pprod,
    float* __restrict__ hin) {
  int gid = blockIdx.x * 256 + threadIdx.x;  // BB*DII*16
  int s_di = gid % (DII * 16);
  int b = gid / (DII * 16);
  float run = 0.f;
#pragma unroll
  for (int c = 0; c < NCH; c++) {
    size_t off = ((size_t)(b * NCH + c) * DII) * 16 + s_di;
    hin[off] = run;
    run = Pprod[off] * run + hloc[off];
  }
}

__global__ __launch_bounds__(256) void ssm_phase3(
    const float* __restrict__ dt, const float* __restrict__ proj,
    const float* __restrict__ u, const float* __restrict__ uz,
    const float* __restrict__ A_log, const float* __restrict__ Dskip,
    const float* __restrict__ hin, __hip_bfloat16* __restrict__ y) {
  int gid = blockIdx.x * 256 + threadIdx.x;  // BB*NCH*DII
  int di = gid % DII;
  int rem = gid / DII;
  int chunk = rem % NCH;
  int b = rem / NCH;
  float a[DSS], h[DSS];
#pragma unroll
  for (int i = 0; i < 4; i++) {
    f32x4 al = *(const f32x4*)&A_log[di * DSS + i * 4];
    f32x4 hl = *(const f32x4*)&hin[(size_t)gid * 16 + i * 4];
#pragma unroll
    for (int j = 0; j < 4; j++) { a[i * 4 + j] = -__expf(al[j]); h[i * 4 + j] = hl[j]; }
  }
  float dsk = Dskip[di];
  int t0 = chunk * LCH;
  for (int lt = 0; lt < LCH; lt++) {
    size_t bt = (size_t)(b * TT + t0 + lt);
    float dtv = dt[bt * DII + di];
    float uv = u[bt * DII + di];
    float zv = uz[bt * (2 * DII) + DII + di];
    const float* pr = proj + bt * 96 + DTRR;
    float dtu = dtv * uv;
    float yp = 0.f;
#pragma unroll
    for (int s = 0; s < DSS; s++) {
      float dA = __expf(dtv * a[s]);
      h[s] = dA * h[s] + dtu * pr[s];
      yp += h[s] * pr[DSS + s];
    }
    float sz = zv / (1.f + __expf(-zv));
    y[bt * DII + di] = __float2bfloat16((yp + uv * dsk) * sz);
  }
}

// ---------------- gather selected tokens (bf16) ----------------
__global__ __launch_bounds__(256) void gather_tok(
    const __hip_bfloat16* __restrict__ xnb, const int* __restrict__ idx,
    __hip_bfloat16* __restrict__ tok) {
  int r = blockIdx.x;
  int b = r / KK;
  int tsel = idx[r];
  const __hip_bfloat16* src = xnb + ((size_t)(b * TT + tsel)) * DD;
  __hip_bfloat16* dst = tok + (size_t)r * DD;
#pragma unroll
  for (int j = 0; j < 4; j++) dst[threadIdx.x + 256 * j] = src[threadIdx.x + 256 * j];
}

// ---------------- MFMA attention: block per (b,h), 13 waves ----------------
#define KP 72
#define VP 232
__global__ __launch_bounds__(832) void attn_mfma_kernel(
    const float* __restrict__ qkv, __hip_bfloat16* __restrict__ attn_o) {
  __shared__ ushort Klds[208 * KP];        // 29952 B
  __shared__ ushort VTlds[64 * VP];        // 29696 B
  __shared__ ushort Plds[13 * 16 * VP];    // 96512 B  (total 152.5 KB)
  int bh = blockIdx.x;
  int h = bh % HH, b = bh / HH;
  int t = threadIdx.x;
  const float* base = qkv + (size_t)(b * KK) * 3072 + h * 64;

  for (int i = t; i < 208 * 64; i += 832) {
    int r = i >> 6, d = i & 63;
    float v = (r < KK) ? base[(size_t)r * 3072 + 1024 + d] : 0.f;
    Klds[r * KP + d] = f2bu(v);
  }
  for (int i = t; i < 208 * 64; i += 832) {
    int r = i >> 6, d = i & 63;
    float v = (r < KK) ? base[(size_t)r * 3072 + 2048 + d] : 0.f;
    VTlds[d * VP + r] = f2bu(v);
  }
  for (int i = t; i < 64 * (VP - 208); i += 832) {
    int d = i / (VP - 208), k = 208 + i % (VP - 208);
    VTlds[d * VP + k] = 0;
  }

  int wv = t >> 6, lane = t & 63;
  int q0 = wv * 16;
  int qrow = q0 + (lane & 15);
  if (qrow > KK - 1) qrow = KK - 1;
  const float* qptr = base + (size_t)qrow * 3072 + ((lane >> 4) * 8);
  bf16x8 qf[2];
#pragma unroll
  for (int ks = 0; ks < 2; ks++) {
    f32x4 lo = *(const f32x4*)(qptr + ks * 32);
    f32x4 hi = *(const f32x4*)(qptr + ks * 32 + 4);
#pragma unroll
    for (int j = 0; j < 4; j++) {
      qf[ks][j] = (short)f2bu(lo[j] * 0.125f);
      qf[ks][j + 4] = (short)f2bu(hi[j] * 0.125f);
    }
  }
  ushort* myP = Plds + wv * 16 * VP;
  for (int i = lane; i < 16 * (VP - 208); i += 64) {
    int r = i / (VP - 208), k = 208 + i % (VP - 208);
    myP[r * VP + k] = 0;
  }
  __syncthreads();

  f32x4 sacc[13] = {};
#pragma unroll
  for (int nt = 0; nt < 13; nt++) {
#pragma unroll
    for (int ks = 0; ks < 2; ks++) {
      bf16x8 kf = *(const bf16x8*)&Klds[(nt * 16 + (lane & 15)) * KP +
                                        ks * 32 + (lane >> 4) * 8];
      sacc[nt] = __builtin_amdgcn_mfma_f32_16x16x32_bf16(qf[ks], kf, sacc[nt], 0, 0, 0);
    }
  }
  if ((lane & 15) >= 12) {
#pragma unroll
    for (int i = 0; i < 4; i++) sacc[12][i] = -1e30f;
  }
  float m4[4], l4[4];
#pragma unroll
  for (int i = 0; i < 4; i++) {
    float m = sacc[0][i];
#pragma unroll
    for (int nt = 1; nt < 13; nt++) m = fmaxf(m, sacc[nt][i]);
    m = fmaxf(m, __shfl_xor(m, 1, 64));
    m = fmaxf(m, __shfl_xor(m, 2, 64));
    m = fmaxf(m, __shfl_xor(m, 4, 64));
    m = fmaxf(m, __shfl_xor(m, 8, 64));
    m4[i] = m;
  }
#pragma unroll
  for (int i = 0; i < 4; i++) {
    float ls = 0.f;
    int prow = (lane >> 4) * 4 + i;
#pragma unroll
    for (int nt = 0; nt < 13; nt++) {
      float e = __expf(sacc[nt][i] - m4[i]);
      ls += e;
      myP[prow * VP + nt * 16 + (lane & 15)] = f2bu(e);
    }
    ls += __shfl_xor(ls, 1, 64);
    ls += __shfl_xor(ls, 2, 64);
    ls += __shfl_xor(ls, 4, 64);
    ls += __shfl_xor(ls, 8, 64);
    l4[i] = ls;
  }
  f32x4 oacc[4] = {};
#pragma unroll
  for (int dt = 0; dt < 4; dt++) {
#pragma unroll
    for (int ks = 0; ks < 7; ks++) {
      bf16x8 pf = *(const bf16x8*)&myP[(lane & 15) * VP + ks * 32 + (lane >> 4) * 8];
      bf16x8 vf = *(const bf16x8*)&VTlds[(dt * 16 + (lane & 15)) * VP +
                                         ks * 32 + (lane >> 4) * 8];
      oacc[dt] = __builtin_amdgcn_mfma_f32_16x16x32_bf16(pf, vf, oacc[dt], 0, 0, 0);
    }
  }
#pragma unroll
  for (int i = 0; i < 4; i++) {
    int row = q0 + (lane >> 4) * 4 + i;
    if (row >= KK) continue;
    float inv = 1.f / l4[i];
#pragma unroll
    for (int dt = 0; dt < 4; dt++) {
      int col = dt * 16 + (lane & 15);
      attn_o[((size_t)(b * KK + row)) * DD + h * 64 + col] =
          __float2bfloat16(oacc[dt][i] * inv);
    }
  }
}

extern "C" void kernel_launch(void* const* d_in, const int* in_sizes, int n_in,
                              void* d_out, int out_size, void* d_ws, size_t ws_size,
                              hipStream_t stream) {
  const float* x = (const float*)d_in[0];
  const float* ln_g = (const float*)d_in[1];
  const float* ln_b = (const float*)d_in[2];
  const float* Wr1 = (const float*)d_in[3];
  const float* br1 = (const float*)d_in[4];
  const float* Wr2 = (const float*)d_in[5];
  const float* br2 = (const float*)d_in[6];
  const float* Wqkv = (const float*)d_in[7];
  const float* bqkv = (const float*)d_in[8];
  const float* Wo = (const float*)d_in[9];
  const float* bo = (const float*)d_in[10];
  const float* W_in = (const float*)d_in[11];
  const float* conv_w = (const float*)d_in[12];
  const float* conv_b = (const float*)d_in[13];
  const float* W_xproj = (const float*)d_in[14];
  const float* W_dt = (const float*)d_in[15];
  const float* b_dt = (const float*)d_in[16];
  const float* A_log = (const float*)d_in[17];
  const float* Dskip = (const float*)d_in[18];
  const float* W_out = (const float*)d_in[19];
  float* out = (float*)d_out;

  float* w = (float*)d_ws;
  size_t o = 0;
  float* xn = w + o;     o += (size_t)BB * TT * DD;
  float* hbuf = w + o;   o += (size_t)BB * TT * 256;
  float* scores = w + o; o += (size_t)BB * TT;
  int* idxb = (int*)(w + o); o += 1024;
  float* uzb = w + o;    o += (size_t)BB * TT * 2 * DII;
  float* ub = w + o;     o += (size_t)BB * TT * DII;
  float* projb = w + o;  o += (size_t)BB * TT * 96;
  float* dtb = w + o;    o += (size_t)BB * TT * DII;
  float* qkvb = w + o;   o += (size_t)BB * KK * 3 * DD;
  float* hloc = w + o;   o += (size_t)BB * NCH * DII * 16;
  float* Pprod = w + o;  o += (size_t)BB * NCH * DII * 16;
  float* hin = w + o;    o += (size_t)BB * NCH * DII * 16;
  __hip_bfloat16* xnb = (__hip_bfloat16*)(w + o);   o += (size_t)BB * TT * DD / 2;
  __hip_bfloat16* yb16 = (__hip_bfloat16*)(w + o);  o += (size_t)BB * TT * DII / 2;
  __hip_bfloat16* tokb = (__hip_bfloat16*)(w + o);  o += (size_t)BB * KK * DD / 2 + 8;
  __hip_bfloat16* attno = (__hip_bfloat16*)(w + o); o += (size_t)BB * KK * DD / 2 + 8;
  __hip_bfloat16* WinT = (__hip_bfloat16*)(w + o);  o += (size_t)(2 * DII) * DD / 2;
  __hip_bfloat16* WoutT = (__hip_bfloat16*)(w + o); o += (size_t)DD * DII / 2;
  __hip_bfloat16* WqkvT = (__hip_bfloat16*)(w + o); o += (size_t)(3 * DD) * DD / 2;
  __hip_bfloat16* WoT = (__hip_bfloat16*)(w + o);   o += (size_t)DD * DD / 2;
  // overlays: router partials -> uzb (33.55 MB, dead until W_in GEMM);
  // xproj partials -> hloc (16.8 MB >= 12.6 MB, dead until ssm_phase1);
  // W_out split-K partials -> uzb (WKSP*4096*1024 = 16.77M floats, exact fit;
  //   uzb dead after ssm_phase3).
  float* rpart = uzb;
  float* xpart = hloc;
  float* wpart = uzb;
  const size_t WZSTR = (size_t)BB * TT * DD;  // 4.19M floats per z-slice

  // 1. layernorm
  layernorm_kernel<<<BB * TT, 256, 0, stream>>>(x, ln_g, ln_b, xn, xnb);
  // weight transposes/converts (bf16 [N,K])
  transpose_bf16<<<dim3(2 * DII / 32, DD / 32), 256, 0, stream>>>(W_in, DD, 2 * DII, WinT);
  transpose_bf16<<<dim3(DD / 32, DII / 32), 256, 0, stream>>>(W_out, DII, DD, WoutT);
  transpose_bf16<<<dim3(3 * DD / 32, DD / 32), 256, 0, stream>>>(Wqkv, DD, 3 * DD, WqkvT);
  transpose_bf16<<<dim3(DD / 32, DD / 32), 256, 0, stream>>>(Wo, DD, DD, WoT);
  // 2. router (fp32 split-K; selection bit-exact)
  gemm_f32_splitk<<<dim3(4, 64, KSPL), 256, 0, stream>>>(
      xn, DD, Wr1, 256, rpart, BB * TT, 256, DD);
  splitk_reduce<<<(BB * TT * 256 + 255) / 256, 256, 0, stream>>>(
      rpart, hbuf, BB * TT * 256, 1);
  router_score_kernel<<<BB * TT, 256, 0, stream>>>(hbuf, Wr2, br2, scores);
  topk_kernel<<<BB, 1024, 0, stream>>>(scores, idxb);
  // 3. SSM branch: uz (256 MFMA) -> conv -> xproj -> dt -> scan -> W_out
  gemm_bf16_256<<<dim3(2 * DII / 256, BB * TT / 256), 512, 0, stream>>>(
      (const ushort*)xnb, DD, (const ushort*)WinT, DD, uzb, 2 * DII, DD,
      nullptr, nullptr);
  conv_silu_kernel<<<(BB * TT * DII) / 1024, 256, 0, stream>>>(uzb, conv_w, conv_b, ub);
  gemm_f32_splitk<<<dim3(2, 64, KSPL), 256, 0, stream>>>(
      ub, DII, W_xproj, XPN, xpart, BB * TT, XPN, DII);
  splitk_reduce<<<(BB * TT * XPN + 255) / 256, 256, 0, stream>>>(
      xpart, projb, BB * TT * XPN, 0);
  gemm_f32<<<dim3(32, 64), 256, 0, stream>>>(projb, 96, W_dt, DII, dtb, DII,
                                             BB * TT, DII, DTRR, b_dt, 2);
  ssm_phase1<<<(BB * NCH * DII) / 256, 256, 0, stream>>>(dtb, projb, ub, A_log,
                                                         hloc, Pprod);
  ssm_phase2<<<(BB * DII * 16) / 256, 256, 0, stream>>>(hloc, Pprod, hin);
  ssm_phase3<<<(BB * NCH * DII) / 256, 256, 0, stream>>>(dtb, projb, ub, uzb,
                                                         A_log, Dskip, hin, yb16);
  // W_out split-K (uzb dead now): partial[z] = y @ W_out (K chunk of 512)
  gemm_bf16_256_splitk<<<dim3(DD / 256, BB * TT / 256, WKSP), 512, 0, stream>>>(
      (const ushort*)yb16, DII, (const ushort*)WoutT, DII, wpart, DD, DII, WZSTR);
  // out = sum_z partial + x
  splitk4_add_reduce<<<(int)(WZSTR / 4 / 256), 256, 0, stream>>>(
      wpart, x, out, WZSTR);
  // 4. attention branch
  gather_tok<<<BB * KK, 256, 0, stream>>>(xnb, idxb, tokb);
  gemm_bf16_mfma<<<dim3(3 * DD / 128, (BB * KK + 127) / 128), 256, 0, stream>>>(
      (const ushort*)tokb, DD, (const ushort*)WqkvT, DD, qkvb, 3 * DD,
      BB * KK, 3 * DD, DD, bqkv, nullptr, nullptr);
  attn_mfma_kernel<<<BB * HH, 832, 0, stream>>>(qkvb, attno);
  // Wo MFMA with fused scatter: out[b, idx[r], :] = acc + bo + x[...]
  gemm_bf16_mfma<<<dim3(DD / 128, (BB * KK + 127) / 128), 256, 0, stream>>>(
      (const ushort*)attno, DD, (const ushort*)WoT, DD, out, DD,
      BB * KK, DD, DD, bo, x, idxb);
}

// Round 11
// 580.924 us; speedup vs baseline: 1.1573x; 1.0209x over previous
//
#include <hip/hip_runtime.h>
#include <hip/hip_bf16.h>
#include <math.h>

#define BB   4
#define TT   1024
#define DD   1024
#define HH   16
#define DII  2048
#define DSS  16
#define DCC  4
#define KK   204
#define HDD  64
#define DTRR 64
#define NCH  32
#define LCH  32    // TT / NCH
#define KSPL 8
#define XPN  96

typedef short bf16x8 __attribute__((ext_vector_type(8)));
typedef float f32x4 __attribute__((ext_vector_type(4)));

#define GLDS16(g, l) __builtin_amdgcn_global_load_lds(                        \
    (const __attribute__((address_space(1))) void*)(g),                       \
    (__attribute__((address_space(3))) void*)(l), 16, 0, 0)

__device__ __forceinline__ ushort f2bu(float v) {
  __hip_bfloat16 h = __float2bfloat16(v);
  return __builtin_bit_cast(ushort, h);
}

// ---------------- reduction helpers ----------------
__device__ __forceinline__ float wave_sum(float v) {
#pragma unroll
  for (int o = 32; o > 0; o >>= 1) v += __shfl_xor(v, o, 64);
  return v;
}
__device__ __forceinline__ float block_sum256(float v, volatile float* sh) {
  v = wave_sum(v);
  if ((threadIdx.x & 63) == 0) sh[threadIdx.x >> 6] = v;
  __syncthreads();
  float r = sh[0] + sh[1] + sh[2] + sh[3];
  __syncthreads();
  return r;
}

// ---------------- layernorm (writes fp32 + bf16) ----------------
__global__ __launch_bounds__(256) void layernorm_kernel(
    const float* __restrict__ x, const float* __restrict__ g,
    const float* __restrict__ be, float* __restrict__ xn,
    __hip_bfloat16* __restrict__ xnb) {
  __shared__ float sh[4];
  int row = blockIdx.x;
  const float* xr = x + (size_t)row * DD;
  float v[4];
  float s = 0.f;
#pragma unroll
  for (int i = 0; i < 4; i++) { v[i] = xr[threadIdx.x + 256 * i]; s += v[i]; }
  float mean = block_sum256(s, sh) * (1.f / DD);
  float q = 0.f;
#pragma unroll
  for (int i = 0; i < 4; i++) { float d = v[i] - mean; q += d * d; }
  float var = block_sum256(q, sh) * (1.f / DD);
  float rstd = rsqrtf(var + 1e-5f);
#pragma unroll
  for (int i = 0; i < 4; i++) {
    int c = threadIdx.x + 256 * i;
    float o = (v[i] - mean) * rstd * g[c] + be[c];
    xn[(size_t)row * DD + c] = o;
    xnb[(size_t)row * DD + c] = __float2bfloat16(o);
  }
}

// ---------------- transpose + convert: W[rows,cols] f32 -> WT[cols,rows] bf16 ----
__global__ __launch_bounds__(256) void transpose_bf16(
    const float* __restrict__ W, int rows, int cols,
    __hip_bfloat16* __restrict__ WT) {
  __shared__ float tile[32][33];
  int c0 = blockIdx.x * 32, r0 = blockIdx.y * 32;
  int tx = threadIdx.x & 31, ty = threadIdx.x >> 5;
#pragma unroll
  for (int i = 0; i < 32; i += 8)
    tile[ty + i][tx] = W[(size_t)(r0 + ty + i) * cols + c0 + tx];
  __syncthreads();
#pragma unroll
  for (int i = 0; i < 32; i += 8)
    WT[(size_t)(c0 + ty + i) * rows + r0 + tx] = __float2bfloat16(tile[tx][ty + i]);
}

// ---------------- 256x256 2-phase bf16 MFMA GEMM (M,N %256, K %64) ----------
__global__ __launch_bounds__(512) void gemm_bf16_256(
    const ushort* __restrict__ A, int lda,
    const ushort* __restrict__ BT, int ldbt,
    float* __restrict__ C, int ldc, int K,
    const float* __restrict__ bias, const float* __restrict__ addmat) {
  __shared__ ushort Alds[256 * 64];   // 32 KB
  __shared__ ushort Blds[256 * 64];   // 32 KB
  int t = threadIdx.x;
  int wv = t >> 6, lane = t & 63;
  int wvm = wv >> 2, wvn = wv & 3;
  int nwg = gridDim.x * gridDim.y;
  int lin = blockIdx.y * gridDim.x + blockIdx.x;
  int swz = (lin & 7) * (nwg >> 3) + (lin >> 3);
  int bx = swz % gridDim.x, by = swz / gridDim.x;
  int row0 = by * 256, col0 = bx * 256;
  f32x4 acc[8][4] = {};

  const ushort* Ap[4];
  const ushort* Bp[4];
  ushort* Alb[4];
  ushort* Blb[4];
#pragma unroll
  for (int j = 0; j < 4; j++) {
    int c = j * 512 + t;
    int r = c >> 3, kc = (c & 7) * 8;
    Ap[j] = A + (size_t)(row0 + r) * lda + kc;
    Bp[j] = BT + (size_t)(col0 + r) * ldbt + kc;
    int cst = j * 512 + wv * 64;          // wave-uniform chunk base
    Alb[j] = Alds + (size_t)cst * 8;
    Blb[j] = Blds + (size_t)cst * 8;
  }
  int frow = lane & 15, fk = (lane >> 4) * 8;

  for (int k0 = 0; k0 < K; k0 += 64) {
#pragma unroll
    for (int j = 0; j < 4; j++) {
      GLDS16(Ap[j] + k0, Alb[j]);
      GLDS16(Bp[j] + k0, Blb[j]);
    }
    __syncthreads();
#pragma unroll
    for (int ks = 0; ks < 2; ks++) {
      bf16x8 af[8], bfv[4];
#pragma unroll
      for (int m = 0; m < 8; m++)
        af[m] = *(const bf16x8*)&Alds[(wvm * 128 + m * 16 + frow) * 64 +
                                      ks * 32 + fk];
#pragma unroll
      for (int n = 0; n < 4; n++)
        bfv[n] = *(const bf16x8*)&Blds[(wvn * 64 + n * 16 + frow) * 64 +
                                       ks * 32 + fk];
#pragma unroll
      for (int m = 0; m < 8; m++)
#pragma unroll
        for (int n = 0; n < 4; n++)
          acc[m][n] = __builtin_amdgcn_mfma_f32_16x16x32_bf16(af[m], bfv[n],
                                                              acc[m][n], 0, 0, 0);
    }
    __syncthreads();
  }
  int rbase = row0 + wvm * 128 + (lane >> 4) * 4;
  int cbase = col0 + wvn * 64 + (lane & 15);
#pragma unroll
  for (int n = 0; n < 4; n++) {
    int cc = cbase + n * 16;
    float bi = bias ? bias[cc] : 0.f;
#pragma unroll
    for (int m = 0; m < 8; m++) {
#pragma unroll
      for (int i = 0; i < 4; i++) {
        size_t r = rbase + m * 16 + i;
        float v = acc[m][n][i] + bi;
        if (addmat) v += addmat[r * ldc + cc];
        C[r * ldc + cc] = v;
      }
    }
  }
}

// ---------------- 128x128 8-wave bf16 MFMA GEMM (M,N %128, K %64) ----------
// 512 thr, 8 waves (4M x 2N), wave tile 32x64, BK=64. act: 0 none, 2 softplus.
__global__ __launch_bounds__(512) void gemm_bf16_128x8(
    const ushort* __restrict__ A, int lda,
    const ushort* __restrict__ BT, int ldbt,
    float* __restrict__ C, int ldc, int K,
    const float* __restrict__ bias, const float* __restrict__ addmat, int act) {
  __shared__ ushort Alds[128 * 64];   // 16 KB
  __shared__ ushort Blds[128 * 64];   // 16 KB
  int t = threadIdx.x;
  int wv = t >> 6, lane = t & 63;
  int wvm = wv >> 1, wvn = wv & 1;
  int nwg = gridDim.x * gridDim.y;
  int lin = blockIdx.y * gridDim.x + blockIdx.x;
  int swz = (lin & 7) * (nwg >> 3) + (lin >> 3);
  int bx = swz % gridDim.x, by = swz / gridDim.x;
  int row0 = by * 128, col0 = bx * 128;
  f32x4 acc[2][4] = {};

  const ushort* Ap[2];
  const ushort* Bp[2];
  ushort* Alb[2];
  ushort* Blb[2];
#pragma unroll
  for (int j = 0; j < 2; j++) {
    int c = j * 512 + t;                  // 1024 chunks of 16B per matrix
    int r = c >> 3, kc = (c & 7) * 8;
    Ap[j] = A + (size_t)(row0 + r) * lda + kc;
    Bp[j] = BT + (size_t)(col0 + r) * ldbt + kc;
    int cst = j * 512 + wv * 64;          // wave-uniform chunk base
    Alb[j] = Alds + (size_t)cst * 8;
    Blb[j] = Blds + (size_t)cst * 8;
  }
  int frow = lane & 15, fk = (lane >> 4) * 8;

  for (int k0 = 0; k0 < K; k0 += 64) {
#pragma unroll
    for (int j = 0; j < 2; j++) {
      GLDS16(Ap[j] + k0, Alb[j]);
      GLDS16(Bp[j] + k0, Blb[j]);
    }
    __syncthreads();
#pragma unroll
    for (int ks = 0; ks < 2; ks++) {
      bf16x8 af[2], bfv[4];
#pragma unroll
      for (int m = 0; m < 2; m++)
        af[m] = *(const bf16x8*)&Alds[(wvm * 32 + m * 16 + frow) * 64 +
                                      ks * 32 + fk];
#pragma unroll
      for (int n = 0; n < 4; n++)
        bfv[n] = *(const bf16x8*)&Blds[(wvn * 64 + n * 16 + frow) * 64 +
                                       ks * 32 + fk];
#pragma unroll
      for (int m = 0; m < 2; m++)
#pragma unroll
        for (int n = 0; n < 4; n++)
          acc[m][n] = __builtin_amdgcn_mfma_f32_16x16x32_bf16(af[m], bfv[n],
                                                              acc[m][n], 0, 0, 0);
    }
    __syncthreads();
  }
  int rbase = row0 + wvm * 32 + (lane >> 4) * 4;
  int cbase = col0 + wvn * 64 + (lane & 15);
#pragma unroll
  for (int n = 0; n < 4; n++) {
    int cc = cbase + n * 16;
    float bi = bias ? bias[cc] : 0.f;
#pragma unroll
    for (int m = 0; m < 2; m++) {
#pragma unroll
      for (int i = 0; i < 4; i++) {
        size_t r = rbase + m * 16 + i;
        float v = acc[m][n][i] + bi;
        if (act == 2) v = (v > 20.f) ? v : log1pf(__expf(v));
        if (addmat) v += addmat[r * ldc + cc];
        C[r * ldc + cc] = v;
      }
    }
  }
}

// ---------------- 128x128 4-wave bf16 MFMA GEMM (bounds-checked) ----------
__global__ __launch_bounds__(256) void gemm_bf16_mfma(
    const ushort* __restrict__ A, int lda,
    const ushort* __restrict__ BT, int ldbt,
    float* __restrict__ C, int ldc,
    int M, int N, int K, const float* __restrict__ bias,
    const float* __restrict__ addmat, const int* __restrict__ rowmap) {
  __shared__ ushort Alds[128 * 32];
  __shared__ ushort Blds[128 * 32];
  int t = threadIdx.x;
  int wv = t >> 6;
  int lane = t & 63;
  int nwg = gridDim.x * gridDim.y;
  int lin = blockIdx.y * gridDim.x + blockIdx.x;
  int swz = (lin & 7) * (nwg >> 3) + (lin >> 3);
  int bx = swz % gridDim.x, by = swz / gridDim.x;
  int row0 = by * 128, col0 = bx * 128;
  int wr = (wv >> 1) * 64, wc = (wv & 1) * 64;
  f32x4 acc[4][4] = {};

  int srow = t >> 2;
  int sk = (t & 3) * 8;
  int ar0 = row0 + srow;       if (ar0 >= M) ar0 = M - 1;
  int ar1 = row0 + 64 + srow;  if (ar1 >= M) ar1 = M - 1;
  int br0 = col0 + srow;       if (br0 >= N) br0 = N - 1;
  int br1 = col0 + 64 + srow;  if (br1 >= N) br1 = N - 1;
  const ushort* Ag0 = A + (size_t)ar0 * lda + sk;
  const ushort* Ag1 = A + (size_t)ar1 * lda + sk;
  const ushort* Bg0 = BT + (size_t)br0 * ldbt + sk;
  const ushort* Bg1 = BT + (size_t)br1 * ldbt + sk;
  ushort* Al = Alds + wv * 512;
  ushort* Bl = Blds + wv * 512;

  int frow = lane & 15;
  int fk = (lane >> 4) * 8;

  for (int k0 = 0; k0 < K; k0 += 32) {
    GLDS16(Ag0 + k0, Al);
    GLDS16(Ag1 + k0, Al + 2048);
    GLDS16(Bg0 + k0, Bl);
    GLDS16(Bg1 + k0, Bl + 2048);
    __syncthreads();
    bf16x8 af[4], bfv[4];
#pragma unroll
    for (int m = 0; m < 4; m++)
      af[m] = *(const bf16x8*)&Alds[(wr + m * 16 + frow) * 32 + fk];
#pragma unroll
    for (int n = 0; n < 4; n++)
      bfv[n] = *(const bf16x8*)&Blds[(wc + n * 16 + frow) * 32 + fk];
#pragma unroll
    for (int m = 0; m < 4; m++)
#pragma unroll
      for (int n = 0; n < 4; n++)
        acc[m][n] = __builtin_amdgcn_mfma_f32_16x16x32_bf16(af[m], bfv[n],
                                                            acc[m][n], 0, 0, 0);
    __syncthreads();
  }
  int rbase = row0 + wr + (lane >> 4) * 4;
  int cbase = col0 + wc + (lane & 15);
#pragma unroll
  for (int n = 0; n < 4; n++) {
    int ccol = cbase + n * 16;
    if (ccol >= N) continue;
    float bi = bias ? bias[ccol] : 0.f;
#pragma unroll
    for (int m = 0; m < 4; m++) {
      int r0_ = rbase + m * 16;
#pragma unroll
      for (int i = 0; i < 4; i++) {
        int r = r0_ + i;
        if (r < M) {
          size_t orow = r;
          if (rowmap) orow = (size_t)((r / KK) * TT + rowmap[r]);
          float v = acc[m][n][i] + bi;
          if (addmat) v += addmat[orow * ldc + ccol];
          C[orow * ldc + ccol] = v;
        }
      }
    }
  }
}

// ---------------- split-K fp32 GEMM: partial[ks] = A@B chunk ----------------
__global__ __launch_bounds__(256) void gemm_f32_splitk(
    const float* __restrict__ A, int lda,
    const float* __restrict__ B, int ldb,
    float* __restrict__ partial,  // [KSPL][M][N]
    int M, int N, int Kd) {
  __shared__ float As[16][65];
  __shared__ float Bs[16][65];
  int tx = threadIdx.x % 16;
  int ty = threadIdx.x / 16;
  int row0 = blockIdx.y * 64, col0 = blockIdx.x * 64;
  int ks = blockIdx.z;
  int kchunk = Kd / KSPL;
  int kbeg = ks * kchunk, kend = kbeg + kchunk;
  float acc[4][4] = {};
  int ar = threadIdx.x / 4;
  int ak = (threadIdx.x % 4) * 4;
  int bc = threadIdx.x % 64;
  int br = threadIdx.x / 64;
  for (int k0 = kbeg; k0 < kend; k0 += 16) {
#pragma unroll
    for (int i = 0; i < 4; i++) {
      int gr = row0 + ar, gk = k0 + ak + i;
      float v = 0.f;
      if (gr < M) v = A[(size_t)gr * lda + gk];
      As[ak + i][ar] = v;
    }
#pragma unroll
    for (int i = 0; i < 4; i++) {
      int gk = k0 + br + 4 * i, gc = col0 + bc;
      float v = 0.f;
      if (gc < N) v = B[(size_t)gk * ldb + gc];
      Bs[br + 4 * i][bc] = v;
    }
    __syncthreads();
#pragma unroll
    for (int kk = 0; kk < 16; kk++) {
      float a[4], b[4];
#pragma unroll
      for (int i = 0; i < 4; i++) a[i] = As[kk][ty * 4 + i];
#pragma unroll
      for (int j = 0; j < 4; j++) b[j] = Bs[kk][tx * 4 + j];
#pragma unroll
      for (int i = 0; i < 4; i++)
#pragma unroll
        for (int j = 0; j < 4; j++) acc[i][j] += a[i] * b[j];
    }
    __syncthreads();
  }
  float* P = partial + (size_t)ks * M * N;
#pragma unroll
  for (int i = 0; i < 4; i++) {
    int r = row0 + ty * 4 + i;
    if (r >= M) continue;
#pragma unroll
    for (int j = 0; j < 4; j++) {
      int c = col0 + tx * 4 + j;
      if (c < N) P[(size_t)r * N + c] = acc[i][j];
    }
  }
}

__global__ __launch_bounds__(256) void splitk_reduce(
    const float* __restrict__ partial, float* __restrict__ C, int MN, int act) {
  int i = blockIdx.x * 256 + threadIdx.x;
  if (i >= MN) return;
  float s = 0.f;
#pragma unroll
  for (int k = 0; k < KSPL; k++) s += partial[(size_t)k * MN + i];
  if (act == 1) s = fmaxf(s, 0.f);
  C[i] = s;
}

// dual-output reduce: fp32 C + bf16 Cb
__global__ __launch_bounds__(256) void splitk_reduce_dual(
    const float* __restrict__ partial, float* __restrict__ C,
    __hip_bfloat16* __restrict__ Cb, int MN) {
  int i = blockIdx.x * 256 + threadIdx.x;
  if (i >= MN) return;
  float s = 0.f;
#pragma unroll
  for (int k = 0; k < KSPL; k++) s += partial[(size_t)k * MN + i];
  C[i] = s;
  Cb[i] = __float2bfloat16(s);
}

// ---------------- router score ----------------
__global__ __launch_bounds__(256) void router_score_kernel(
    const float* __restrict__ h, const float* __restrict__ Wr2,
    const float* __restrict__ br2, float* __restrict__ scores) {
  __shared__ float sh[4];
  int row = blockIdx.x;
  float v = h[(size_t)row * 256 + threadIdx.x] * Wr2[threadIdx.x];
  float s = block_sum256(v, sh);
  if (threadIdx.x == 0) scores[row] = s + br2[0];
}

// ---------------- exact top-K per batch (bitonic) ----------------
__global__ __launch_bounds__(1024) void topk_kernel(
    const float* __restrict__ scores, int* __restrict__ idx) {
  __shared__ float s[1024];
  __shared__ int si[1024];
  int b = blockIdx.x, t = threadIdx.x;
  s[t] = scores[b * TT + t];
  si[t] = t;
  __syncthreads();
  for (int k = 2; k <= 1024; k <<= 1) {
    for (int j = k >> 1; j > 0; j >>= 1) {
      int partner = t ^ j;
      if (partner > t) {
        bool dirDesc = ((t & k) == 0);
        float s1 = s[t], s2 = s[partner];
        int i1 = si[t], i2 = si[partner];
        bool firstGreater = (s1 > s2) || (s1 == s2 && i1 < i2);
        bool doSwap = dirDesc ? !firstGreater : firstGreater;
        if (doSwap) { s[t] = s2; s[partner] = s1; si[t] = i2; si[partner] = i1; }
      }
      __syncthreads();
    }
  }
  if (t < KK) idx[b * KK + t] = si[t];
}

// ---------------- causal conv (DC=4) + silu, 4 channels/thread ----------------
__global__ __launch_bounds__(256) void conv_silu_kernel(
    const float* __restrict__ uz, const float* __restrict__ conv_w,
    const float* __restrict__ conv_b, float* __restrict__ u) {
  size_t gid4 = ((size_t)blockIdx.x * 256 + threadIdx.x) * 4;  // over B*T*DI
  int c = gid4 % DII;
  size_t bt = gid4 / DII;
  int t = bt % TT;
  int b = bt / TT;
  f32x4 cw[4];
#pragma unroll
  for (int ci = 0; ci < 4; ci++) cw[ci] = *(const f32x4*)&conv_w[(c + ci) * DCC];
  f32x4 sum = *(const f32x4*)&conv_b[c];
#pragma unroll
  for (int j = 0; j < DCC; j++) {
    int tt = t - (DCC - 1) + j;
    if (tt >= 0) {
      f32x4 uv = *(const f32x4*)&uz[((size_t)(b * TT + tt)) * (2 * DII) + c];
#pragma unroll
      for (int ci = 0; ci < 4; ci++) sum[ci] += uv[ci] * cw[ci][j];
    }
  }
  f32x4 r;
#pragma unroll
  for (int ci = 0; ci < 4; ci++) r[ci] = sum[ci] / (1.f + __expf(-sum[ci]));
  *(f32x4*)&u[gid4] = r;
}

// ---------------- chunked selective scan (states in registers) ----------------
__global__ __launch_bounds__(256) void ssm_phase1(
    const float* __restrict__ dt, const float* __restrict__ proj,
    const float* __restrict__ u, const float* __restrict__ A_log,
    float* __restrict__ hloc, float* __restrict__ Pprod) {
  int gid = blockIdx.x * 256 + threadIdx.x;  // BB*NCH*DII
  int di = gid % DII;
  int rem = gid / DII;
  int chunk = rem % NCH;
  int b = rem / NCH;
  float a[DSS], h[DSS], P[DSS];
#pragma unroll
  for (int i = 0; i < 4; i++) {
    f32x4 al = *(const f32x4*)&A_log[di * DSS + i * 4];
#pragma unroll
    for (int j = 0; j < 4; j++) a[i * 4 + j] = -__expf(al[j]);
  }
#pragma unroll
  for (int s = 0; s < DSS; s++) { h[s] = 0.f; P[s] = 1.f; }
  int t0 = chunk * LCH;
  for (int lt = 0; lt < LCH; lt++) {
    size_t bt = (size_t)(b * TT + t0 + lt);
    float dtv = dt[bt * DII + di];
    float uv = u[bt * DII + di];
    const float* pr = proj + bt * 96 + DTRR;
    float dtu = dtv * uv;
#pragma unroll
    for (int s = 0; s < DSS; s++) {
      float dA = __expf(dtv * a[s]);
      h[s] = dA * h[s] + dtu * pr[s];
      P[s] *= dA;
    }
  }
#pragma unroll
  for (int i = 0; i < 4; i++) {
    *(f32x4*)&hloc[(size_t)gid * 16 + i * 4] = *(f32x4*)&h[i * 4];
    *(f32x4*)&Pprod[(size_t)gid * 16 + i * 4] = *(f32x4*)&P[i * 4];
  }
}

__global__ __launch_bounds__(256) void ssm_phase2(
    const float* __restrict__ hloc, const float* __restrict__ Pprod,
    float* __restrict__ hin) {
  int gid = blockIdx.x * 256 + threadIdx.x;  // BB*DII*16
  int s_di = gid % (DII * 16);
  int b = gid / (DII * 16);
  float run = 0.f;
#pragma unroll
  for (int c = 0; c < NCH; c++) {
    size_t off = ((size_t)(b * NCH + c) * DII) * 16 + s_di;
    hin[off] = run;
    run = Pprod[off] * run + hloc[off];
  }
}

__global__ __launch_bounds__(256) void ssm_phase3(
    const float* __restrict__ dt, const float* __restrict__ proj,
    const float* __restrict__ u, const float* __restrict__ uz,
    const float* __restrict__ A_log, const float* __restrict__ Dskip,
    const float* __restrict__ hin, __hip_bfloat16* __restrict__ y) {
  int gid = blockIdx.x * 256 + threadIdx.x;  // BB*NCH*DII
  int di = gid % DII;
  int rem = gid / DII;
  int chunk = rem % NCH;
  int b = rem / NCH;
  float a[DSS], h[DSS];
#pragma unroll
  for (int i = 0; i < 4; i++) {
    f32x4 al = *(const f32x4*)&A_log[di * DSS + i * 4];
    f32x4 hl = *(const f32x4*)&hin[(size_t)gid * 16 + i * 4];
#pragma unroll
    for (int j = 0; j < 4; j++) { a[i * 4 + j] = -__expf(al[j]); h[i * 4 + j] = hl[j]; }
  }
  float dsk = Dskip[di];
  int t0 = chunk * LCH;
  for (int lt = 0; lt < LCH; lt++) {
    size_t bt = (size_t)(b * TT + t0 + lt);
    float dtv = dt[bt * DII + di];
    float uv = u[bt * DII + di];
    float zv = uz[bt * (2 * DII) + DII + di];
    const float* pr = proj + bt * 96 + DTRR;
    float dtu = dtv * uv;
    float yp = 0.f;
#pragma unroll
    for (int s = 0; s < DSS; s++) {
      float dA = __expf(dtv * a[s]);
      h[s] = dA * h[s] + dtu * pr[s];
      yp += h[s] * pr[DSS + s];
    }
    float sz = zv / (1.f + __expf(-zv));
    y[bt * DII + di] = __float2bfloat16((yp + uv * dsk) * sz);
  }
}

// ---------------- gather selected tokens (bf16) ----------------
__global__ __launch_bounds__(256) void gather_tok(
    const __hip_bfloat16* __restrict__ xnb, const int* __restrict__ idx,
    __hip_bfloat16* __restrict__ tok) {
  int r = blockIdx.x;
  int b = r / KK;
  int tsel = idx[r];
  const __hip_bfloat16* src = xnb + ((size_t)(b * TT + tsel)) * DD;
  __hip_bfloat16* dst = tok + (size_t)r * DD;
#pragma unroll
  for (int j = 0; j < 4; j++) dst[threadIdx.x + 256 * j] = src[threadIdx.x + 256 * j];
}

// ---------------- MFMA attention: block per (b,h), 13 waves ----------------
#define KP 72
#define VP 232
__global__ __launch_bounds__(832) void attn_mfma_kernel(
    const float* __restrict__ qkv, __hip_bfloat16* __restrict__ attn_o) {
  __shared__ ushort Klds[208 * KP];        // 29952 B
  __shared__ ushort VTlds[64 * VP];        // 29696 B
  __shared__ ushort Plds[13 * 16 * VP];    // 96512 B  (total 152.5 KB)
  int bh = blockIdx.x;
  int h = bh % HH, b = bh / HH;
  int t = threadIdx.x;
  const float* base = qkv + (size_t)(b * KK) * 3072 + h * 64;

  for (int i = t; i < 208 * 64; i += 832) {
    int r = i >> 6, d = i & 63;
    float v = (r < KK) ? base[(size_t)r * 3072 + 1024 + d] : 0.f;
    Klds[r * KP + d] = f2bu(v);
  }
  for (int i = t; i < 208 * 64; i += 832) {
    int r = i >> 6, d = i & 63;
    float v = (r < KK) ? base[(size_t)r * 3072 + 2048 + d] : 0.f;
    VTlds[d * VP + r] = f2bu(v);
  }
  for (int i = t; i < 64 * (VP - 208); i += 832) {
    int d = i / (VP - 208), k = 208 + i % (VP - 208);
    VTlds[d * VP + k] = 0;
  }

  int wv = t >> 6, lane = t & 63;
  int q0 = wv * 16;
  int qrow = q0 + (lane & 15);
  if (qrow > KK - 1) qrow = KK - 1;
  const float* qptr = base + (size_t)qrow * 3072 + ((lane >> 4) * 8);
  bf16x8 qf[2];
#pragma unroll
  for (int ks = 0; ks < 2; ks++) {
    f32x4 lo = *(const f32x4*)(qptr + ks * 32);
    f32x4 hi = *(const f32x4*)(qptr + ks * 32 + 4);
#pragma unroll
    for (int j = 0; j < 4; j++) {
      qf[ks][j] = (short)f2bu(lo[j] * 0.125f);
      qf[ks][j + 4] = (short)f2bu(hi[j] * 0.125f);
    }
  }
  ushort* myP = Plds + wv * 16 * VP;
  for (int i = lane; i < 16 * (VP - 208); i += 64) {
    int r = i / (VP - 208), k = 208 + i % (VP - 208);
    myP[r * VP + k] = 0;
  }
  __syncthreads();

  f32x4 sacc[13] = {};
#pragma unroll
  for (int nt = 0; nt < 13; nt++) {
#pragma unroll
    for (int ks = 0; ks < 2; ks++) {
      bf16x8 kf = *(const bf16x8*)&Klds[(nt * 16 + (lane & 15)) * KP +
                                        ks * 32 + (lane >> 4) * 8];
      sacc[nt] = __builtin_amdgcn_mfma_f32_16x16x32_bf16(qf[ks], kf, sacc[nt], 0, 0, 0);
    }
  }
  if ((lane & 15) >= 12) {
#pragma unroll
    for (int i = 0; i < 4; i++) sacc[12][i] = -1e30f;
  }
  float m4[4], l4[4];
#pragma unroll
  for (int i = 0; i < 4; i++) {
    float m = sacc[0][i];
#pragma unroll
    for (int nt = 1; nt < 13; nt++) m = fmaxf(m, sacc[nt][i]);
    m = fmaxf(m, __shfl_xor(m, 1, 64));
    m = fmaxf(m, __shfl_xor(m, 2, 64));
    m = fmaxf(m, __shfl_xor(m, 4, 64));
    m = fmaxf(m, __shfl_xor(m, 8, 64));
    m4[i] = m;
  }
#pragma unroll
  for (int i = 0; i < 4; i++) {
    float ls = 0.f;
    int prow = (lane >> 4) * 4 + i;
#pragma unroll
    for (int nt = 0; nt < 13; nt++) {
      float e = __expf(sacc[nt][i] - m4[i]);
      ls += e;
      myP[prow * VP + nt * 16 + (lane & 15)] = f2bu(e);
    }
    ls += __shfl_xor(ls, 1, 64);
    ls += __shfl_xor(ls, 2, 64);
    ls += __shfl_xor(ls, 4, 64);
    ls += __shfl_xor(ls, 8, 64);
    l4[i] = ls;
  }
  f32x4 oacc[4] = {};
#pragma unroll
  for (int dt = 0; dt < 4; dt++) {
#pragma unroll
    for (int ks = 0; ks < 7; ks++) {
      bf16x8 pf = *(const bf16x8*)&myP[(lane & 15) * VP + ks * 32 + (lane >> 4) * 8];
      bf16x8 vf = *(const bf16x8*)&VTlds[(dt * 16 + (lane & 15)) * VP +
                                         ks * 32 + (lane >> 4) * 8];
      oacc[dt] = __builtin_amdgcn_mfma_f32_16x16x32_bf16(pf, vf, oacc[dt], 0, 0, 0);
    }
  }
#pragma unroll
  for (int i = 0; i < 4; i++) {
    int row = q0 + (lane >> 4) * 4 + i;
    if (row >= KK) continue;
    float inv = 1.f / l4[i];
#pragma unroll
    for (int dt = 0; dt < 4; dt++) {
      int col = dt * 16 + (lane & 15);
      attn_o[((size_t)(b * KK + row)) * DD + h * 64 + col] =
          __float2bfloat16(oacc[dt][i] * inv);
    }
  }
}

extern "C" void kernel_launch(void* const* d_in, const int* in_sizes, int n_in,
                              void* d_out, int out_size, void* d_ws, size_t ws_size,
                              hipStream_t stream) {
  const float* x = (const float*)d_in[0];
  const float* ln_g = (const float*)d_in[1];
  const float* ln_b = (const float*)d_in[2];
  const float* Wr1 = (const float*)d_in[3];
  const float* br1 = (const float*)d_in[4];
  const float* Wr2 = (const float*)d_in[5];
  const float* br2 = (const float*)d_in[6];
  const float* Wqkv = (const float*)d_in[7];
  const float* bqkv = (const float*)d_in[8];
  const float* Wo = (const float*)d_in[9];
  const float* bo = (const float*)d_in[10];
  const float* W_in = (const float*)d_in[11];
  const float* conv_w = (const float*)d_in[12];
  const float* conv_b = (const float*)d_in[13];
  const float* W_xproj = (const float*)d_in[14];
  const float* W_dt = (const float*)d_in[15];
  const float* b_dt = (const float*)d_in[16];
  const float* A_log = (const float*)d_in[17];
  const float* Dskip = (const float*)d_in[18];
  const float* W_out = (const float*)d_in[19];
  float* out = (float*)d_out;

  float* w = (float*)d_ws;
  size_t o = 0;
  float* xn = w + o;     o += (size_t)BB * TT * DD;
  float* hbuf = w + o;   o += (size_t)BB * TT * 256;
  float* scores = w + o; o += (size_t)BB * TT;
  int* idxb = (int*)(w + o); o += 1024;
  float* uzb = w + o;    o += (size_t)BB * TT * 2 * DII;
  float* ub = w + o;     o += (size_t)BB * TT * DII;
  float* projb = w + o;  o += (size_t)BB * TT * 96;
  float* dtb = w + o;    o += (size_t)BB * TT * DII;
  float* qkvb = w + o;   o += (size_t)BB * KK * 3 * DD;
  float* hloc = w + o;   o += (size_t)BB * NCH * DII * 16;
  float* Pprod = w + o;  o += (size_t)BB * NCH * DII * 16;
  float* hin = w + o;    o += (size_t)BB * NCH * DII * 16;
  __hip_bfloat16* xnb = (__hip_bfloat16*)(w + o);   o += (size_t)BB * TT * DD / 2;
  __hip_bfloat16* yb16 = (__hip_bfloat16*)(w + o);  o += (size_t)BB * TT * DII / 2;
  __hip_bfloat16* tokb = (__hip_bfloat16*)(w + o);  o += (size_t)BB * KK * DD / 2 + 8;
  __hip_bfloat16* attno = (__hip_bfloat16*)(w + o); o += (size_t)BB * KK * DD / 2 + 8;
  __hip_bfloat16* projb16 = (__hip_bfloat16*)(w + o); o += (size_t)BB * TT * 96 / 2 + 8;
  __hip_bfloat16* WinT = (__hip_bfloat16*)(w + o);  o += (size_t)(2 * DII) * DD / 2;
  __hip_bfloat16* WoutT = (__hip_bfloat16*)(w + o); o += (size_t)DD * DII / 2;
  __hip_bfloat16* WqkvT = (__hip_bfloat16*)(w + o); o += (size_t)(3 * DD) * DD / 2;
  __hip_bfloat16* WoT = (__hip_bfloat16*)(w + o);   o += (size_t)DD * DD / 2;
  __hip_bfloat16* WdtT = (__hip_bfloat16*)(w + o);  o += (size_t)DII * DTRR / 2;
  // overlays: router partials -> uzb (33.55 MB, dead until W_in GEMM);
  // xproj partials -> hloc (16.8 MB >= 12.6 MB, dead until ssm_phase1).
  float* rpart = uzb;
  float* xpart = hloc;

  // 1. layernorm
  layernorm_kernel<<<BB * TT, 256, 0, stream>>>(x, ln_g, ln_b, xn, xnb);
  // weight transposes/converts (bf16 [N,K])
  transpose_bf16<<<dim3(2 * DII / 32, DD / 32), 256, 0, stream>>>(W_in, DD, 2 * DII, WinT);
  transpose_bf16<<<dim3(DD / 32, DII / 32), 256, 0, stream>>>(W_out, DII, DD, WoutT);
  transpose_bf16<<<dim3(3 * DD / 32, DD / 32), 256, 0, stream>>>(Wqkv, DD, 3 * DD, WqkvT);
  transpose_bf16<<<dim3(DD / 32, DD / 32), 256, 0, stream>>>(Wo, DD, DD, WoT);
  transpose_bf16<<<dim3(DII / 32, DTRR / 32), 256, 0, stream>>>(W_dt, DTRR, DII, WdtT);
  // 2. router (fp32 split-K; selection bit-exact)
  gemm_f32_splitk<<<dim3(4, 64, KSPL), 256, 0, stream>>>(
      xn, DD, Wr1, 256, rpart, BB * TT, 256, DD);
  splitk_reduce<<<(BB * TT * 256 + 255) / 256, 256, 0, stream>>>(
      rpart, hbuf, BB * TT * 256, 1);
  router_score_kernel<<<BB * TT, 256, 0, stream>>>(hbuf, Wr2, br2, scores);
  topk_kernel<<<BB, 1024, 0, stream>>>(scores, idxb);
  // 3. SSM branch: uz (256 MFMA) -> conv -> xproj -> dt (MFMA) -> scan -> W_out
  gemm_bf16_256<<<dim3(2 * DII / 256, BB * TT / 256), 512, 0, stream>>>(
      (const ushort*)xnb, DD, (const ushort*)WinT, DD, uzb, 2 * DII, DD,
      nullptr, nullptr);
  conv_silu_kernel<<<(BB * TT * DII) / 1024, 256, 0, stream>>>(uzb, conv_w, conv_b, ub);
  gemm_f32_splitk<<<dim3(2, 64, KSPL), 256, 0, stream>>>(
      ub, DII, W_xproj, XPN, xpart, BB * TT, XPN, DII);
  splitk_reduce_dual<<<(BB * TT * XPN + 255) / 256, 256, 0, stream>>>(
      xpart, projb, projb16, BB * TT * XPN);
  // dt = softplus(proj[:, :64] @ W_dt + b_dt)  via 8-wave MFMA (K=64)
  gemm_bf16_128x8<<<dim3(DII / 128, BB * TT / 128), 512, 0, stream>>>(
      (const ushort*)projb16, XPN, (const ushort*)WdtT, DTRR, dtb, DII, DTRR,
      b_dt, nullptr, 2);
  ssm_phase1<<<(BB * NCH * DII) / 256, 256, 0, stream>>>(dtb, projb, ub, A_log,
                                                         hloc, Pprod);
  ssm_phase2<<<(BB * DII * 16) / 256, 256, 0, stream>>>(hloc, Pprod, hin);
  ssm_phase3<<<(BB * NCH * DII) / 256, 256, 0, stream>>>(dtb, projb, ub, uzb,
                                                         A_log, Dskip, hin, yb16);
  // out = y@W_out + x (8-wave 128x128, fused residual, single pass)
  gemm_bf16_128x8<<<dim3(DD / 128, BB * TT / 128), 512, 0, stream>>>(
      (const ushort*)yb16, DII, (const ushort*)WoutT, DII, out, DD, DII,
      nullptr, x, 0);
  // 4. attention branch
  gather_tok<<<BB * KK, 256, 0, stream>>>(xnb, idxb, tokb);
  gemm_bf16_mfma<<<dim3(3 * DD / 128, (BB * KK + 127) / 128), 256, 0, stream>>>(
      (const ushort*)tokb, DD, (const ushort*)WqkvT, DD, qkvb, 3 * DD,
      BB * KK, 3 * DD, DD, bqkv, nullptr, nullptr);
  attn_mfma_kernel<<<BB * HH, 832, 0, stream>>>(qkvb, attno);
  // Wo MFMA with fused scatter: out[b, idx[r], :] = acc + bo + x[...]
  gemm_bf16_mfma<<<dim3(DD / 128, (BB * KK + 127) / 128), 256, 0, stream>>>(
      (const ushort*)attno, DD, (const ushort*)WoT, DD, out, DD,
      BB * KK, DD, DD, bo, x, idxb);
}

// Round 12
// 560.088 us; speedup vs baseline: 1.2004x; 1.0372x over previous
//
#include <hip/hip_runtime.h>
#include <hip/hip_bf16.h>
#include <math.h>

#define BB   4
#define TT   1024
#define DD   1024
#define HH   16
#define DII  2048
#define DSS  16
#define DCC  4
#define KK   204
#define HDD  64
#define DTRR 64
#define NCH  32
#define LCH  32    // TT / NCH
#define KSPL 8
#define XPN  96

typedef short bf16x8 __attribute__((ext_vector_type(8)));
typedef float f32x4 __attribute__((ext_vector_type(4)));

#define GLDS16(g, l) __builtin_amdgcn_global_load_lds(                        \
    (const __attribute__((address_space(1))) void*)(g),                       \
    (__attribute__((address_space(3))) void*)(l), 16, 0, 0)

__device__ __forceinline__ ushort f2bu(float v) {
  __hip_bfloat16 h = __float2bfloat16(v);
  return __builtin_bit_cast(ushort, h);
}

// ---------------- reduction helpers ----------------
__device__ __forceinline__ float wave_sum(float v) {
#pragma unroll
  for (int o = 32; o > 0; o >>= 1) v += __shfl_xor(v, o, 64);
  return v;
}
__device__ __forceinline__ float block_sum256(float v, volatile float* sh) {
  v = wave_sum(v);
  if ((threadIdx.x & 63) == 0) sh[threadIdx.x >> 6] = v;
  __syncthreads();
  float r = sh[0] + sh[1] + sh[2] + sh[3];
  __syncthreads();
  return r;
}

// ---------------- layernorm (writes fp32 + bf16) ----------------
__global__ __launch_bounds__(256) void layernorm_kernel(
    const float* __restrict__ x, const float* __restrict__ g,
    const float* __restrict__ be, float* __restrict__ xn,
    __hip_bfloat16* __restrict__ xnb) {
  __shared__ float sh[4];
  int row = blockIdx.x;
  const float* xr = x + (size_t)row * DD;
  float v[4];
  float s = 0.f;
#pragma unroll
  for (int i = 0; i < 4; i++) { v[i] = xr[threadIdx.x + 256 * i]; s += v[i]; }
  float mean = block_sum256(s, sh) * (1.f / DD);
  float q = 0.f;
#pragma unroll
  for (int i = 0; i < 4; i++) { float d = v[i] - mean; q += d * d; }
  float var = block_sum256(q, sh) * (1.f / DD);
  float rstd = rsqrtf(var + 1e-5f);
#pragma unroll
  for (int i = 0; i < 4; i++) {
    int c = threadIdx.x + 256 * i;
    float o = (v[i] - mean) * rstd * g[c] + be[c];
    xn[(size_t)row * DD + c] = o;
    xnb[(size_t)row * DD + c] = __float2bfloat16(o);
  }
}

// ---------------- transpose + convert: W[rows,cols] f32 -> WT[cols,rows] bf16 ----
__global__ __launch_bounds__(256) void transpose_bf16(
    const float* __restrict__ W, int rows, int cols,
    __hip_bfloat16* __restrict__ WT) {
  __shared__ float tile[32][33];
  int c0 = blockIdx.x * 32, r0 = blockIdx.y * 32;
  int tx = threadIdx.x & 31, ty = threadIdx.x >> 5;
#pragma unroll
  for (int i = 0; i < 32; i += 8)
    tile[ty + i][tx] = W[(size_t)(r0 + ty + i) * cols + c0 + tx];
  __syncthreads();
#pragma unroll
  for (int i = 0; i < 32; i += 8)
    WT[(size_t)(c0 + ty + i) * rows + r0 + tx] = __float2bfloat16(tile[tx][ty + i]);
}

// ---------------- 256x256 2-phase bf16 MFMA GEMM (M,N %256, K %64) ----------
// T2 XOR swizzle: LDS physical col = logical col ^ ((row&7)*8) elements
// (pre-swizzled global source + swizzled ds_read; involution, rule #21).
__global__ __launch_bounds__(512) void gemm_bf16_256(
    const ushort* __restrict__ A, int lda,
    const ushort* __restrict__ BT, int ldbt,
    float* __restrict__ C, int ldc, int K,
    const float* __restrict__ bias, const float* __restrict__ addmat) {
  __shared__ ushort Alds[256 * 64];   // 32 KB
  __shared__ ushort Blds[256 * 64];   // 32 KB
  int t = threadIdx.x;
  int wv = t >> 6, lane = t & 63;
  int wvm = wv >> 2, wvn = wv & 3;
  int nwg = gridDim.x * gridDim.y;
  int lin = blockIdx.y * gridDim.x + blockIdx.x;
  int swz = (lin & 7) * (nwg >> 3) + (lin >> 3);
  int bx = swz % gridDim.x, by = swz / gridDim.x;
  int row0 = by * 256, col0 = bx * 256;
  f32x4 acc[8][4] = {};

  const ushort* Ap[4];
  const ushort* Bp[4];
  ushort* Alb[4];
  ushort* Blb[4];
#pragma unroll
  for (int j = 0; j < 4; j++) {
    int c = j * 512 + t;
    int r = c >> 3;
    int kc = (((c & 7) ^ (r & 7)) * 8);   // swizzled source column
    Ap[j] = A + (size_t)(row0 + r) * lda + kc;
    Bp[j] = BT + (size_t)(col0 + r) * ldbt + kc;
    int cst = j * 512 + wv * 64;          // wave-uniform chunk base
    Alb[j] = Alds + (size_t)cst * 8;
    Blb[j] = Blds + (size_t)cst * 8;
  }
  int frow = lane & 15, fk = (lane >> 4) * 8;

  for (int k0 = 0; k0 < K; k0 += 64) {
#pragma unroll
    for (int j = 0; j < 4; j++) {
      GLDS16(Ap[j] + k0, Alb[j]);
      GLDS16(Bp[j] + k0, Blb[j]);
    }
    __syncthreads();
#pragma unroll
    for (int ks = 0; ks < 2; ks++) {
      bf16x8 af[8], bfv[4];
#pragma unroll
      for (int m = 0; m < 8; m++) {
        int row = wvm * 128 + m * 16 + frow;
        af[m] = *(const bf16x8*)&Alds[row * 64 +
                                      ((ks * 32 + fk) ^ ((row & 7) * 8))];
      }
#pragma unroll
      for (int n = 0; n < 4; n++) {
        int row = wvn * 64 + n * 16 + frow;
        bfv[n] = *(const bf16x8*)&Blds[row * 64 +
                                       ((ks * 32 + fk) ^ ((row & 7) * 8))];
      }
#pragma unroll
      for (int m = 0; m < 8; m++)
#pragma unroll
        for (int n = 0; n < 4; n++)
          acc[m][n] = __builtin_amdgcn_mfma_f32_16x16x32_bf16(af[m], bfv[n],
                                                              acc[m][n], 0, 0, 0);
    }
    __syncthreads();
  }
  int rbase = row0 + wvm * 128 + (lane >> 4) * 4;
  int cbase = col0 + wvn * 64 + (lane & 15);
#pragma unroll
  for (int n = 0; n < 4; n++) {
    int cc = cbase + n * 16;
    float bi = bias ? bias[cc] : 0.f;
#pragma unroll
    for (int m = 0; m < 8; m++) {
#pragma unroll
      for (int i = 0; i < 4; i++) {
        size_t r = rbase + m * 16 + i;
        float v = acc[m][n][i] + bi;
        if (addmat) v += addmat[r * ldc + cc];
        C[r * ldc + cc] = v;
      }
    }
  }
}

// ---------------- 128x128 8-wave bf16 MFMA GEMM (M,N %128, K %64) ----------
// Same T2 swizzle. 512 thr, 8 waves (4M x 2N), wave tile 32x64, BK=64.
__global__ __launch_bounds__(512) void gemm_bf16_128x8(
    const ushort* __restrict__ A, int lda,
    const ushort* __restrict__ BT, int ldbt,
    float* __restrict__ C, int ldc, int K,
    const float* __restrict__ bias, const float* __restrict__ addmat, int act) {
  __shared__ ushort Alds[128 * 64];   // 16 KB
  __shared__ ushort Blds[128 * 64];   // 16 KB
  int t = threadIdx.x;
  int wv = t >> 6, lane = t & 63;
  int wvm = wv >> 1, wvn = wv & 1;
  int nwg = gridDim.x * gridDim.y;
  int lin = blockIdx.y * gridDim.x + blockIdx.x;
  int swz = (lin & 7) * (nwg >> 3) + (lin >> 3);
  int bx = swz % gridDim.x, by = swz / gridDim.x;
  int row0 = by * 128, col0 = bx * 128;
  f32x4 acc[2][4] = {};

  const ushort* Ap[2];
  const ushort* Bp[2];
  ushort* Alb[2];
  ushort* Blb[2];
#pragma unroll
  for (int j = 0; j < 2; j++) {
    int c = j * 512 + t;                  // 1024 chunks of 16B per matrix
    int r = c >> 3;
    int kc = (((c & 7) ^ (r & 7)) * 8);   // swizzled source column
    Ap[j] = A + (size_t)(row0 + r) * lda + kc;
    Bp[j] = BT + (size_t)(col0 + r) * ldbt + kc;
    int cst = j * 512 + wv * 64;          // wave-uniform chunk base
    Alb[j] = Alds + (size_t)cst * 8;
    Blb[j] = Blds + (size_t)cst * 8;
  }
  int frow = lane & 15, fk = (lane >> 4) * 8;

  for (int k0 = 0; k0 < K; k0 += 64) {
#pragma unroll
    for (int j = 0; j < 2; j++) {
      GLDS16(Ap[j] + k0, Alb[j]);
      GLDS16(Bp[j] + k0, Blb[j]);
    }
    __syncthreads();
#pragma unroll
    for (int ks = 0; ks < 2; ks++) {
      bf16x8 af[2], bfv[4];
#pragma unroll
      for (int m = 0; m < 2; m++) {
        int row = wvm * 32 + m * 16 + frow;
        af[m] = *(const bf16x8*)&Alds[row * 64 +
                                      ((ks * 32 + fk) ^ ((row & 7) * 8))];
      }
#pragma unroll
      for (int n = 0; n < 4; n++) {
        int row = wvn * 64 + n * 16 + frow;
        bfv[n] = *(const bf16x8*)&Blds[row * 64 +
                                       ((ks * 32 + fk) ^ ((row & 7) * 8))];
      }
#pragma unroll
      for (int m = 0; m < 2; m++)
#pragma unroll
        for (int n = 0; n < 4; n++)
          acc[m][n] = __builtin_amdgcn_mfma_f32_16x16x32_bf16(af[m], bfv[n],
                                                              acc[m][n], 0, 0, 0);
    }
    __syncthreads();
  }
  int rbase = row0 + wvm * 32 + (lane >> 4) * 4;
  int cbase = col0 + wvn * 64 + (lane & 15);
#pragma unroll
  for (int n = 0; n < 4; n++) {
    int cc = cbase + n * 16;
    float bi = bias ? bias[cc] : 0.f;
#pragma unroll
    for (int m = 0; m < 2; m++) {
#pragma unroll
      for (int i = 0; i < 4; i++) {
        size_t r = rbase + m * 16 + i;
        float v = acc[m][n][i] + bi;
        if (act == 2) v = (v > 20.f) ? v : log1pf(__expf(v));
        if (addmat) v += addmat[r * ldc + cc];
        C[r * ldc + cc] = v;
      }
    }
  }
}

// ---------------- 128x128 4-wave bf16 MFMA GEMM (bounds-checked) ----------
// BK=32 (64B rows): 2-bit swizzle col ^= ((row&3)*8) -> 4-way residual.
__global__ __launch_bounds__(256) void gemm_bf16_mfma(
    const ushort* __restrict__ A, int lda,
    const ushort* __restrict__ BT, int ldbt,
    float* __restrict__ C, int ldc,
    int M, int N, int K, const float* __restrict__ bias,
    const float* __restrict__ addmat, const int* __restrict__ rowmap) {
  __shared__ ushort Alds[128 * 32];
  __shared__ ushort Blds[128 * 32];
  int t = threadIdx.x;
  int wv = t >> 6;
  int lane = t & 63;
  int nwg = gridDim.x * gridDim.y;
  int lin = blockIdx.y * gridDim.x + blockIdx.x;
  int swz = (lin & 7) * (nwg >> 3) + (lin >> 3);
  int bx = swz % gridDim.x, by = swz / gridDim.x;
  int row0 = by * 128, col0 = bx * 128;
  int wr = (wv >> 1) * 64, wc = (wv & 1) * 64;
  f32x4 acc[4][4] = {};

  int srow = t >> 2;
  int sk = (((t & 3) ^ (srow & 3)) * 8);  // swizzled source column
  int ar0 = row0 + srow;       if (ar0 >= M) ar0 = M - 1;
  int ar1 = row0 + 64 + srow;  if (ar1 >= M) ar1 = M - 1;
  int br0 = col0 + srow;       if (br0 >= N) br0 = N - 1;
  int br1 = col0 + 64 + srow;  if (br1 >= N) br1 = N - 1;
  const ushort* Ag0 = A + (size_t)ar0 * lda + sk;
  const ushort* Ag1 = A + (size_t)ar1 * lda + sk;
  const ushort* Bg0 = BT + (size_t)br0 * ldbt + sk;
  const ushort* Bg1 = BT + (size_t)br1 * ldbt + sk;
  ushort* Al = Alds + wv * 512;
  ushort* Bl = Blds + wv * 512;

  int frow = lane & 15;
  int fk = (lane >> 4) * 8;

  for (int k0 = 0; k0 < K; k0 += 32) {
    GLDS16(Ag0 + k0, Al);
    GLDS16(Ag1 + k0, Al + 2048);
    GLDS16(Bg0 + k0, Bl);
    GLDS16(Bg1 + k0, Bl + 2048);
    __syncthreads();
    bf16x8 af[4], bfv[4];
#pragma unroll
    for (int m = 0; m < 4; m++) {
      int row = wr + m * 16 + frow;
      af[m] = *(const bf16x8*)&Alds[row * 32 + (fk ^ ((row & 3) * 8))];
    }
#pragma unroll
    for (int n = 0; n < 4; n++) {
      int row = wc + n * 16 + frow;
      bfv[n] = *(const bf16x8*)&Blds[row * 32 + (fk ^ ((row & 3) * 8))];
    }
#pragma unroll
    for (int m = 0; m < 4; m++)
#pragma unroll
      for (int n = 0; n < 4; n++)
        acc[m][n] = __builtin_amdgcn_mfma_f32_16x16x32_bf16(af[m], bfv[n],
                                                            acc[m][n], 0, 0, 0);
    __syncthreads();
  }
  int rbase = row0 + wr + (lane >> 4) * 4;
  int cbase = col0 + wc + (lane & 15);
#pragma unroll
  for (int n = 0; n < 4; n++) {
    int ccol = cbase + n * 16;
    if (ccol >= N) continue;
    float bi = bias ? bias[ccol] : 0.f;
#pragma unroll
    for (int m = 0; m < 4; m++) {
      int r0_ = rbase + m * 16;
#pragma unroll
      for (int i = 0; i < 4; i++) {
        int r = r0_ + i;
        if (r < M) {
          size_t orow = r;
          if (rowmap) orow = (size_t)((r / KK) * TT + rowmap[r]);
          float v = acc[m][n][i] + bi;
          if (addmat) v += addmat[orow * ldc + ccol];
          C[orow * ldc + ccol] = v;
        }
      }
    }
  }
}

// ---------------- split-K fp32 GEMM: partial[ks] = A@B chunk ----------------
__global__ __launch_bounds__(256) void gemm_f32_splitk(
    const float* __restrict__ A, int lda,
    const float* __restrict__ B, int ldb,
    float* __restrict__ partial,  // [KSPL][M][N]
    int M, int N, int Kd) {
  __shared__ float As[16][65];
  __shared__ float Bs[16][65];
  int tx = threadIdx.x % 16;
  int ty = threadIdx.x / 16;
  int row0 = blockIdx.y * 64, col0 = blockIdx.x * 64;
  int ks = blockIdx.z;
  int kchunk = Kd / KSPL;
  int kbeg = ks * kchunk, kend = kbeg + kchunk;
  float acc[4][4] = {};
  int ar = threadIdx.x / 4;
  int ak = (threadIdx.x % 4) * 4;
  int bc = threadIdx.x % 64;
  int br = threadIdx.x / 64;
  for (int k0 = kbeg; k0 < kend; k0 += 16) {
#pragma unroll
    for (int i = 0; i < 4; i++) {
      int gr = row0 + ar, gk = k0 + ak + i;
      float v = 0.f;
      if (gr < M) v = A[(size_t)gr * lda + gk];
      As[ak + i][ar] = v;
    }
#pragma unroll
    for (int i = 0; i < 4; i++) {
      int gk = k0 + br + 4 * i, gc = col0 + bc;
      float v = 0.f;
      if (gc < N) v = B[(size_t)gk * ldb + gc];
      Bs[br + 4 * i][bc] = v;
    }
    __syncthreads();
#pragma unroll
    for (int kk = 0; kk < 16; kk++) {
      float a[4], b[4];
#pragma unroll
      for (int i = 0; i < 4; i++) a[i] = As[kk][ty * 4 + i];
#pragma unroll
      for (int j = 0; j < 4; j++) b[j] = Bs[kk][tx * 4 + j];
#pragma unroll
      for (int i = 0; i < 4; i++)
#pragma unroll
        for (int j = 0; j < 4; j++) acc[i][j] += a[i] * b[j];
    }
    __syncthreads();
  }
  float* P = partial + (size_t)ks * M * N;
#pragma unroll
  for (int i = 0; i < 4; i++) {
    int r = row0 + ty * 4 + i;
    if (r >= M) continue;
#pragma unroll
    for (int j = 0; j < 4; j++) {
      int c = col0 + tx * 4 + j;
      if (c < N) P[(size_t)r * N + c] = acc[i][j];
    }
  }
}

__global__ __launch_bounds__(256) void splitk_reduce(
    const float* __restrict__ partial, float* __restrict__ C, int MN, int act) {
  int i = blockIdx.x * 256 + threadIdx.x;
  if (i >= MN) return;
  float s = 0.f;
#pragma unroll
  for (int k = 0; k < KSPL; k++) s += partial[(size_t)k * MN + i];
  if (act == 1) s = fmaxf(s, 0.f);
  C[i] = s;
}

// dual-output reduce: fp32 C + bf16 Cb
__global__ __launch_bounds__(256) void splitk_reduce_dual(
    const float* __restrict__ partial, float* __restrict__ C,
    __hip_bfloat16* __restrict__ Cb, int MN) {
  int i = blockIdx.x * 256 + threadIdx.x;
  if (i >= MN) return;
  float s = 0.f;
#pragma unroll
  for (int k = 0; k < KSPL; k++) s += partial[(size_t)k * MN + i];
  C[i] = s;
  Cb[i] = __float2bfloat16(s);
}

// ---------------- router score ----------------
__global__ __launch_bounds__(256) void router_score_kernel(
    const float* __restrict__ h, const float* __restrict__ Wr2,
    const float* __restrict__ br2, float* __restrict__ scores) {
  __shared__ float sh[4];
  int row = blockIdx.x;
  float v = h[(size_t)row * 256 + threadIdx.x] * Wr2[threadIdx.x];
  float s = block_sum256(v, sh);
  if (threadIdx.x == 0) scores[row] = s + br2[0];
}

// ---------------- exact top-K per batch (bitonic) ----------------
__global__ __launch_bounds__(1024) void topk_kernel(
    const float* __restrict__ scores, int* __restrict__ idx) {
  __shared__ float s[1024];
  __shared__ int si[1024];
  int b = blockIdx.x, t = threadIdx.x;
  s[t] = scores[b * TT + t];
  si[t] = t;
  __syncthreads();
  for (int k = 2; k <= 1024; k <<= 1) {
    for (int j = k >> 1; j > 0; j >>= 1) {
      int partner = t ^ j;
      if (partner > t) {
        bool dirDesc = ((t & k) == 0);
        float s1 = s[t], s2 = s[partner];
        int i1 = si[t], i2 = si[partner];
        bool firstGreater = (s1 > s2) || (s1 == s2 && i1 < i2);
        bool doSwap = dirDesc ? !firstGreater : firstGreater;
        if (doSwap) { s[t] = s2; s[partner] = s1; si[t] = i2; si[partner] = i1; }
      }
      __syncthreads();
    }
  }
  if (t < KK) idx[b * KK + t] = si[t];
}

// ---------------- causal conv (DC=4) + silu, 4 channels/thread ----------------
__global__ __launch_bounds__(256) void conv_silu_kernel(
    const float* __restrict__ uz, const float* __restrict__ conv_w,
    const float* __restrict__ conv_b, float* __restrict__ u) {
  size_t gid4 = ((size_t)blockIdx.x * 256 + threadIdx.x) * 4;  // over B*T*DI
  int c = gid4 % DII;
  size_t bt = gid4 / DII;
  int t = bt % TT;
  int b = bt / TT;
  f32x4 cw[4];
#pragma unroll
  for (int ci = 0; ci < 4; ci++) cw[ci] = *(const f32x4*)&conv_w[(c + ci) * DCC];
  f32x4 sum = *(const f32x4*)&conv_b[c];
#pragma unroll
  for (int j = 0; j < DCC; j++) {
    int tt = t - (DCC - 1) + j;
    if (tt >= 0) {
      f32x4 uv = *(const f32x4*)&uz[((size_t)(b * TT + tt)) * (2 * DII) + c];
#pragma unroll
      for (int ci = 0; ci < 4; ci++) sum[ci] += uv[ci] * cw[ci][j];
    }
  }
  f32x4 r;
#pragma unroll
  for (int ci = 0; ci < 4; ci++) r[ci] = sum[ci] / (1.f + __expf(-sum[ci]));
  *(f32x4*)&u[gid4] = r;
}

// ---------------- chunked selective scan (states in registers) ----------------
__global__ __launch_bounds__(256) void ssm_phase1(
    const float* __restrict__ dt, const float* __restrict__ proj,
    const float* __restrict__ u, const float* __restrict__ A_log,
    float* __restrict__ hloc, float* __restrict__ Pprod) {
  int gid = blockIdx.x * 256 + threadIdx.x;  // BB*NCH*DII
  int di = gid % DII;
  int rem = gid / DII;
  int chunk = rem % NCH;
  int b = rem / NCH;
  float a[DSS], h[DSS], P[DSS];
#pragma unroll
  for (int i = 0; i < 4; i++) {
    f32x4 al = *(const f32x4*)&A_log[di * DSS + i * 4];
#pragma unroll
    for (int j = 0; j < 4; j++) a[i * 4 + j] = -__expf(al[j]);
  }
#pragma unroll
  for (int s = 0; s < DSS; s++) { h[s] = 0.f; P[s] = 1.f; }
  int t0 = chunk * LCH;
  for (int lt = 0; lt < LCH; lt++) {
    size_t bt = (size_t)(b * TT + t0 + lt);
    float dtv = dt[bt * DII + di];
    float uv = u[bt * DII + di];
    const float* pr = proj + bt * 96 + DTRR;
    float dtu = dtv * uv;
#pragma unroll
    for (int s = 0; s < DSS; s++) {
      float dA = __expf(dtv * a[s]);
      h[s] = dA * h[s] + dtu * pr[s];
      P[s] *= dA;
    }
  }
#pragma unroll
  for (int i = 0; i < 4; i++) {
    *(f32x4*)&hloc[(size_t)gid * 16 + i * 4] = *(f32x4*)&h[i * 4];
    *(f32x4*)&Pprod[(size_t)gid * 16 + i * 4] = *(f32x4*)&P[i * 4];
  }
}

__global__ __launch_bounds__(256) void ssm_phase2(
    const float* __restrict__ hloc, const float* __restrict__ Pprod,
    float* __restrict__ hin) {
  int gid = blockIdx.x * 256 + threadIdx.x;  // BB*DII*16
  int s_di = gid % (DII * 16);
  int b = gid / (DII * 16);
  float run = 0.f;
#pragma unroll
  for (int c = 0; c < NCH; c++) {
    size_t off = ((size_t)(b * NCH + c) * DII) * 16 + s_di;
    hin[off] = run;
    run = Pprod[off] * run + hloc[off];
  }
}

__global__ __launch_bounds__(256) void ssm_phase3(
    const float* __restrict__ dt, const float* __restrict__ proj,
    const float* __restrict__ u, const float* __restrict__ uz,
    const float* __restrict__ A_log, const float* __restrict__ Dskip,
    const float* __restrict__ hin, __hip_bfloat16* __restrict__ y) {
  int gid = blockIdx.x * 256 + threadIdx.x;  // BB*NCH*DII
  int di = gid % DII;
  int rem = gid / DII;
  int chunk = rem % NCH;
  int b = rem / NCH;
  float a[DSS], h[DSS];
#pragma unroll
  for (int i = 0; i < 4; i++) {
    f32x4 al = *(const f32x4*)&A_log[di * DSS + i * 4];
    f32x4 hl = *(const f32x4*)&hin[(size_t)gid * 16 + i * 4];
#pragma unroll
    for (int j = 0; j < 4; j++) { a[i * 4 + j] = -__expf(al[j]); h[i * 4 + j] = hl[j]; }
  }
  float dsk = Dskip[di];
  int t0 = chunk * LCH;
  for (int lt = 0; lt < LCH; lt++) {
    size_t bt = (size_t)(b * TT + t0 + lt);
    float dtv = dt[bt * DII + di];
    float uv = u[bt * DII + di];
    float zv = uz[bt * (2 * DII) + DII + di];
    const float* pr = proj + bt * 96 + DTRR;
    float dtu = dtv * uv;
    float yp = 0.f;
#pragma unroll
    for (int s = 0; s < DSS; s++) {
      float dA = __expf(dtv * a[s]);
      h[s] = dA * h[s] + dtu * pr[s];
      yp += h[s] * pr[DSS + s];
    }
    float sz = zv / (1.f + __expf(-zv));
    y[bt * DII + di] = __float2bfloat16((yp + uv * dsk) * sz);
  }
}

// ---------------- gather selected tokens (bf16) ----------------
__global__ __launch_bounds__(256) void gather_tok(
    const __hip_bfloat16* __restrict__ xnb, const int* __restrict__ idx,
    __hip_bfloat16* __restrict__ tok) {
  int r = blockIdx.x;
  int b = r / KK;
  int tsel = idx[r];
  const __hip_bfloat16* src = xnb + ((size_t)(b * TT + tsel)) * DD;
  __hip_bfloat16* dst = tok + (size_t)r * DD;
#pragma unroll
  for (int j = 0; j < 4; j++) dst[threadIdx.x + 256 * j] = src[threadIdx.x + 256 * j];
}

// ---------------- MFMA attention: block per (b,h), 13 waves ----------------
#define KP 72
#define VP 232
__global__ __launch_bounds__(832) void attn_mfma_kernel(
    const float* __restrict__ qkv, __hip_bfloat16* __restrict__ attn_o) {
  __shared__ ushort Klds[208 * KP];        // 29952 B
  __shared__ ushort VTlds[64 * VP];        // 29696 B
  __shared__ ushort Plds[13 * 16 * VP];    // 96512 B  (total 152.5 KB)
  int bh = blockIdx.x;
  int h = bh % HH, b = bh / HH;
  int t = threadIdx.x;
  const float* base = qkv + (size_t)(b * KK) * 3072 + h * 64;

  for (int i = t; i < 208 * 64; i += 832) {
    int r = i >> 6, d = i & 63;
    float v = (r < KK) ? base[(size_t)r * 3072 + 1024 + d] : 0.f;
    Klds[r * KP + d] = f2bu(v);
  }
  for (int i = t; i < 208 * 64; i += 832) {
    int r = i >> 6, d = i & 63;
    float v = (r < KK) ? base[(size_t)r * 3072 + 2048 + d] : 0.f;
    VTlds[d * VP + r] = f2bu(v);
  }
  for (int i = t; i < 64 * (VP - 208); i += 832) {
    int d = i / (VP - 208), k = 208 + i % (VP - 208);
    VTlds[d * VP + k] = 0;
  }

  int wv = t >> 6, lane = t & 63;
  int q0 = wv * 16;
  int qrow = q0 + (lane & 15);
  if (qrow > KK - 1) qrow = KK - 1;
  const float* qptr = base + (size_t)qrow * 3072 + ((lane >> 4) * 8);
  bf16x8 qf[2];
#pragma unroll
  for (int ks = 0; ks < 2; ks++) {
    f32x4 lo = *(const f32x4*)(qptr + ks * 32);
    f32x4 hi = *(const f32x4*)(qptr + ks * 32 + 4);
#pragma unroll
    for (int j = 0; j < 4; j++) {
      qf[ks][j] = (short)f2bu(lo[j] * 0.125f);
      qf[ks][j + 4] = (short)f2bu(hi[j] * 0.125f);
    }
  }
  ushort* myP = Plds + wv * 16 * VP;
  for (int i = lane; i < 16 * (VP - 208); i += 64) {
    int r = i / (VP - 208), k = 208 + i % (VP - 208);
    myP[r * VP + k] = 0;
  }
  __syncthreads();

  f32x4 sacc[13] = {};
#pragma unroll
  for (int nt = 0; nt < 13; nt++) {
#pragma unroll
    for (int ks = 0; ks < 2; ks++) {
      bf16x8 kf = *(const bf16x8*)&Klds[(nt * 16 + (lane & 15)) * KP +
                                        ks * 32 + (lane >> 4) * 8];
      sacc[nt] = __builtin_amdgcn_mfma_f32_16x16x32_bf16(qf[ks], kf, sacc[nt], 0, 0, 0);
    }
  }
  if ((lane & 15) >= 12) {
#pragma unroll
    for (int i = 0; i < 4; i++) sacc[12][i] = -1e30f;
  }
  float m4[4], l4[4];
#pragma unroll
  for (int i = 0; i < 4; i++) {
    float m = sacc[0][i];
#pragma unroll
    for (int nt = 1; nt < 13; nt++) m = fmaxf(m, sacc[nt][i]);
    m = fmaxf(m, __shfl_xor(m, 1, 64));
    m = fmaxf(m, __shfl_xor(m, 2, 64));
    m = fmaxf(m, __shfl_xor(m, 4, 64));
    m = fmaxf(m, __shfl_xor(m, 8, 64));
    m4[i] = m;
  }
#pragma unroll
  for (int i = 0; i < 4; i++) {
    float ls = 0.f;
    int prow = (lane >> 4) * 4 + i;
#pragma unroll
    for (int nt = 0; nt < 13; nt++) {
      float e = __expf(sacc[nt][i] - m4[i]);
      ls += e;
      myP[prow * VP + nt * 16 + (lane & 15)] = f2bu(e);
    }
    ls += __shfl_xor(ls, 1, 64);
    ls += __shfl_xor(ls, 2, 64);
    ls += __shfl_xor(ls, 4, 64);
    ls += __shfl_xor(ls, 8, 64);
    l4[i] = ls;
  }
  f32x4 oacc[4] = {};
#pragma unroll
  for (int dt = 0; dt < 4; dt++) {
#pragma unroll
    for (int ks = 0; ks < 7; ks++) {
      bf16x8 pf = *(const bf16x8*)&myP[(lane & 15) * VP + ks * 32 + (lane >> 4) * 8];
      bf16x8 vf = *(const bf16x8*)&VTlds[(dt * 16 + (lane & 15)) * VP +
                                         ks * 32 + (lane >> 4) * 8];
      oacc[dt] = __builtin_amdgcn_mfma_f32_16x16x32_bf16(pf, vf, oacc[dt], 0, 0, 0);
    }
  }
#pragma unroll
  for (int i = 0; i < 4; i++) {
    int row = q0 + (lane >> 4) * 4 + i;
    if (row >= KK) continue;
    float inv = 1.f / l4[i];
#pragma unroll
    for (int dt = 0; dt < 4; dt++) {
      int col = dt * 16 + (lane & 15);
      attn_o[((size_t)(b * KK + row)) * DD + h * 64 + col] =
          __float2bfloat16(oacc[dt][i] * inv);
    }
  }
}

extern "C" void kernel_launch(void* const* d_in, const int* in_sizes, int n_in,
                              void* d_out, int out_size, void* d_ws, size_t ws_size,
                              hipStream_t stream) {
  const float* x = (const float*)d_in[0];
  const float* ln_g = (const float*)d_in[1];
  const float* ln_b = (const float*)d_in[2];
  const float* Wr1 = (const float*)d_in[3];
  const float* br1 = (const float*)d_in[4];
  const float* Wr2 = (const float*)d_in[5];
  const float* br2 = (const float*)d_in[6];
  const float* Wqkv = (const float*)d_in[7];
  const float* bqkv = (const float*)d_in[8];
  const float* Wo = (const float*)d_in[9];
  const float* bo = (const float*)d_in[10];
  const float* W_in = (const float*)d_in[11];
  const float* conv_w = (const float*)d_in[12];
  const float* conv_b = (const float*)d_in[13];
  const float* W_xproj = (const float*)d_in[14];
  const float* W_dt = (const float*)d_in[15];
  const float* b_dt = (const float*)d_in[16];
  const float* A_log = (const float*)d_in[17];
  const float* Dskip = (const float*)d_in[18];
  const float* W_out = (const float*)d_in[19];
  float* out = (float*)d_out;

  float* w = (float*)d_ws;
  size_t o = 0;
  float* xn = w + o;     o += (size_t)BB * TT * DD;
  float* hbuf = w + o;   o += (size_t)BB * TT * 256;
  float* scores = w + o; o += (size_t)BB * TT;
  int* idxb = (int*)(w + o); o += 1024;
  float* uzb = w + o;    o += (size_t)BB * TT * 2 * DII;
  float* ub = w + o;     o += (size_t)BB * TT * DII;
  float* projb = w + o;  o += (size_t)BB * TT * 96;
  float* dtb = w + o;    o += (size_t)BB * TT * DII;
  float* qkvb = w + o;   o += (size_t)BB * KK * 3 * DD;
  float* hloc = w + o;   o += (size_t)BB * NCH * DII * 16;
  float* Pprod = w + o;  o += (size_t)BB * NCH * DII * 16;
  float* hin = w + o;    o += (size_t)BB * NCH * DII * 16;
  __hip_bfloat16* xnb = (__hip_bfloat16*)(w + o);   o += (size_t)BB * TT * DD / 2;
  __hip_bfloat16* yb16 = (__hip_bfloat16*)(w + o);  o += (size_t)BB * TT * DII / 2;
  __hip_bfloat16* tokb = (__hip_bfloat16*)(w + o);  o += (size_t)BB * KK * DD / 2 + 8;
  __hip_bfloat16* attno = (__hip_bfloat16*)(w + o); o += (size_t)BB * KK * DD / 2 + 8;
  __hip_bfloat16* projb16 = (__hip_bfloat16*)(w + o); o += (size_t)BB * TT * 96 / 2 + 8;
  __hip_bfloat16* WinT = (__hip_bfloat16*)(w + o);  o += (size_t)(2 * DII) * DD / 2;
  __hip_bfloat16* WoutT = (__hip_bfloat16*)(w + o); o += (size_t)DD * DII / 2;
  __hip_bfloat16* WqkvT = (__hip_bfloat16*)(w + o); o += (size_t)(3 * DD) * DD / 2;
  __hip_bfloat16* WoT = (__hip_bfloat16*)(w + o);   o += (size_t)DD * DD / 2;
  __hip_bfloat16* WdtT = (__hip_bfloat16*)(w + o);  o += (size_t)DII * DTRR / 2;
  // overlays: router partials -> uzb (33.55 MB, dead until W_in GEMM);
  // xproj partials -> hloc (16.8 MB >= 12.6 MB, dead until ssm_phase1).
  float* rpart = uzb;
  float* xpart = hloc;

  // 1. layernorm
  layernorm_kernel<<<BB * TT, 256, 0, stream>>>(x, ln_g, ln_b, xn, xnb);
  // weight transposes/converts (bf16 [N,K])
  transpose_bf16<<<dim3(2 * DII / 32, DD / 32), 256, 0, stream>>>(W_in, DD, 2 * DII, WinT);
  transpose_bf16<<<dim3(DD / 32, DII / 32), 256, 0, stream>>>(W_out, DII, DD, WoutT);
  transpose_bf16<<<dim3(3 * DD / 32, DD / 32), 256, 0, stream>>>(Wqkv, DD, 3 * DD, WqkvT);
  transpose_bf16<<<dim3(DD / 32, DD / 32), 256, 0, stream>>>(Wo, DD, DD, WoT);
  transpose_bf16<<<dim3(DII / 32, DTRR / 32), 256, 0, stream>>>(W_dt, DTRR, DII, WdtT);
  // 2. router (fp32 split-K; selection bit-exact)
  gemm_f32_splitk<<<dim3(4, 64, KSPL), 256, 0, stream>>>(
      xn, DD, Wr1, 256, rpart, BB * TT, 256, DD);
  splitk_reduce<<<(BB * TT * 256 + 255) / 256, 256, 0, stream>>>(
      rpart, hbuf, BB * TT * 256, 1);
  router_score_kernel<<<BB * TT, 256, 0, stream>>>(hbuf, Wr2, br2, scores);
  topk_kernel<<<BB, 1024, 0, stream>>>(scores, idxb);
  // 3. SSM branch: uz (256 MFMA) -> conv -> xproj -> dt (MFMA) -> scan -> W_out
  gemm_bf16_256<<<dim3(2 * DII / 256, BB * TT / 256), 512, 0, stream>>>(
      (const ushort*)xnb, DD, (const ushort*)WinT, DD, uzb, 2 * DII, DD,
      nullptr, nullptr);
  conv_silu_kernel<<<(BB * TT * DII) / 1024, 256, 0, stream>>>(uzb, conv_w, conv_b, ub);
  gemm_f32_splitk<<<dim3(2, 64, KSPL), 256, 0, stream>>>(
      ub, DII, W_xproj, XPN, xpart, BB * TT, XPN, DII);
  splitk_reduce_dual<<<(BB * TT * XPN + 255) / 256, 256, 0, stream>>>(
      xpart, projb, projb16, BB * TT * XPN);
  // dt = softplus(proj[:, :64] @ W_dt + b_dt)  via 8-wave MFMA (K=64)
  gemm_bf16_128x8<<<dim3(DII / 128, BB * TT / 128), 512, 0, stream>>>(
      (const ushort*)projb16, XPN, (const ushort*)WdtT, DTRR, dtb, DII, DTRR,
      b_dt, nullptr, 2);
  ssm_phase1<<<(BB * NCH * DII) / 256, 256, 0, stream>>>(dtb, projb, ub, A_log,
                                                         hloc, Pprod);
  ssm_phase2<<<(BB * DII * 16) / 256, 256, 0, stream>>>(hloc, Pprod, hin);
  ssm_phase3<<<(BB * NCH * DII) / 256, 256, 0, stream>>>(dtb, projb, ub, uzb,
                                                         A_log, Dskip, hin, yb16);
  // out = y@W_out + x (8-wave 128x128, fused residual, single pass)
  gemm_bf16_128x8<<<dim3(DD / 128, BB * TT / 128), 512, 0, stream>>>(
      (const ushort*)yb16, DII, (const ushort*)WoutT, DII, out, DD, DII,
      nullptr, x, 0);
  // 4. attention branch
  gather_tok<<<BB * KK, 256, 0, stream>>>(xnb, idxb, tokb);
  gemm_bf16_mfma<<<dim3(3 * DD / 128, (BB * KK + 127) / 128), 256, 0, stream>>>(
      (const ushort*)tokb, DD, (const ushort*)WqkvT, DD, qkvb, 3 * DD,
      BB * KK, 3 * DD, DD, bqkv, nullptr, nullptr);
  attn_mfma_kernel<<<BB * HH, 832, 0, stream>>>(qkvb, attno);
  // Wo MFMA with fused scatter: out[b, idx[r], :] = acc + bo + x[...]
  gemm_bf16_mfma<<<dim3(DD / 128, (BB * KK + 127) / 128), 256, 0, stream>>>(
      (const ushort*)attno, DD, (const ushort*)WoT, DD, out, DD,
      BB * KK, DD, DD, bo, x, idxb);
}